// Round 1
// baseline (493.400 us; speedup 1.0000x reference)
//
#include <hip/hip_runtime.h>
#include <math.h>

#define N_NODES 50000
#define N_EDGES 800000
#define D_INF   256
#define D_HID   64
#define D_OUTF  32
#define LEAKY   0.2f

__device__ __forceinline__ float leaky_relu(float x){ return x >= 0.f ? x : LEAKY * x; }

// ---------------- CSR build ----------------
__global__ void k_deg(const int* __restrict__ dst, int* __restrict__ deg){
  int i = blockIdx.x * blockDim.x + threadIdx.x;
  if (i < N_EDGES) atomicAdd(&deg[dst[i]], 1);
}

__global__ void k_scan(const int* __restrict__ deg, int* __restrict__ rowptr){
  __shared__ int wsum[16];
  __shared__ int s_carry;
  int t = threadIdx.x, lane = t & 63, wv = t >> 6;
  if (t == 0){ s_carry = 0; rowptr[0] = 0; }
  __syncthreads();
  for (int base = 0; base < N_NODES; base += 1024){
    int i = base + t;
    int x = (i < N_NODES) ? deg[i] : 0;
    // inclusive wave scan
    for (int off = 1; off < 64; off <<= 1){
      int y = __shfl_up(x, off, 64);
      if (lane >= off) x += y;
    }
    if (lane == 63) wsum[wv] = x;
    __syncthreads();
    if (t < 16){
      int w = wsum[t];
      for (int off = 1; off < 16; off <<= 1){
        int y = __shfl_up(w, off, 64);
        if (t >= off) w += y;
      }
      wsum[t] = w;  // inclusive scan of wave sums
    }
    __syncthreads();
    int waveoff = (wv == 0) ? 0 : wsum[wv - 1];
    int incl = s_carry + waveoff + x;
    if (i < N_NODES) rowptr[i + 1] = incl;
    __syncthreads();
    if (t == 0) s_carry += wsum[15];
    __syncthreads();
  }
}

__global__ void k_fill(const int* __restrict__ src, const int* __restrict__ dst,
                       const int* __restrict__ rowptr, int* __restrict__ wcount,
                       int* __restrict__ srcs, int* __restrict__ eidx){
  int i = blockIdx.x * blockDim.x + threadIdx.x;
  if (i < N_EDGES){
    int d = dst[i];
    int pos = rowptr[d] + atomicAdd(&wcount[d], 1);
    srcs[pos] = src[i];
    eidx[pos] = i;
  }
}

// ---------------- layer 1 GEMM: h1 = x@W1, es1/ed1 attention dots ----------------
__global__ __launch_bounds__(256) void k_gemm1(const float* __restrict__ x,
        const float* __restrict__ W1,
        const float* __restrict__ a_src, const float* __restrict__ a_dst,
        float* __restrict__ h1, float* __restrict__ es, float* __restrict__ ed){
  __shared__ float sW[D_INF * D_HID];        // 64 KiB
  int t = threadIdx.x, lane = t & 63, wv = t >> 6;
  {
    const float4* Wg = (const float4*)W1;
    float4* Ws = (float4*)sW;
    for (int idx = t; idx < D_INF * D_HID / 4; idx += 256) Ws[idx] = Wg[idx];
  }
  __syncthreads();
  float as = a_src[lane], ad = a_dst[lane];
  int nw = gridDim.x * 4;
  for (int row = blockIdx.x * 4 + wv; row < N_NODES; row += nw){
    const float4* xr = (const float4*)(x + (size_t)row * D_INF);
    float acc = 0.f;
    #pragma unroll 8
    for (int k4 = 0; k4 < D_INF / 4; ++k4){
      float4 xv = xr[k4];
      acc = fmaf(xv.x, sW[(k4*4+0)*D_HID + lane], acc);
      acc = fmaf(xv.y, sW[(k4*4+1)*D_HID + lane], acc);
      acc = fmaf(xv.z, sW[(k4*4+2)*D_HID + lane], acc);
      acc = fmaf(xv.w, sW[(k4*4+3)*D_HID + lane], acc);
    }
    h1[(size_t)row * D_HID + lane] = acc;
    float vs = acc * as, vd = acc * ad;
    for (int off = 32; off; off >>= 1){
      vs += __shfl_xor(vs, off, 64);
      vd += __shfl_xor(vd, off, 64);
    }
    if (lane == 0){ es[row] = vs; ed[row] = vd; }
  }
}

// ---------------- layer 1 aggregation + bias + ELU ----------------
__global__ __launch_bounds__(256) void k_agg1(const int* __restrict__ rowptr,
      const int* __restrict__ srcs,
      const float* __restrict__ h1, const float* __restrict__ es,
      const float* __restrict__ ed, const float* __restrict__ b1,
      float* __restrict__ h1act){
  int t = threadIdx.x, lane = t & 63, wv = t >> 6;
  int node = blockIdx.x * 4 + wv;
  if (node >= N_NODES) return;
  int beg = rowptr[node], end = rowptr[node + 1];
  float edv = ed[node];
  float mloc = -INFINITY;
  for (int i = beg + lane; i < end; i += 64){
    int s = srcs[i];
    mloc = fmaxf(mloc, leaky_relu(es[s] + edv));
  }
  for (int off = 32; off; off >>= 1) mloc = fmaxf(mloc, __shfl_xor(mloc, off, 64));
  float acc = 0.f, ssum = 0.f;
  for (int i = beg; i < end; ++i){
    int s = srcs[i];                        // broadcast (uniform) load
    float p = __expf(leaky_relu(es[s] + edv) - mloc);
    ssum += p;
    acc = fmaf(p, h1[(size_t)s * D_HID + lane], acc);   // coalesced 256B gather
  }
  float o = acc / (ssum + 1e-16f) + b1[lane];
  h1act[(size_t)node * D_HID + lane] = o > 0.f ? o : expm1f(o);
}

// ---------------- layers 2&3 GEMM (interleaved h23) ----------------
__global__ __launch_bounds__(256) void k_gemm23(const float* __restrict__ h1a,
   const float* __restrict__ W2, const float* __restrict__ W3,
   const float* __restrict__ a2s, const float* __restrict__ a2d,
   const float* __restrict__ a3s, const float* __restrict__ a3d,
   float* __restrict__ h23, float* __restrict__ es2, float* __restrict__ ed2,
   float* __restrict__ es3, float* __restrict__ ed3){
  __shared__ float sW[D_HID * 64];          // [k][half*32+c], 16 KiB
  int t = threadIdx.x, lane = t & 63, wv = t >> 6;
  int half = lane >> 5, c = lane & 31;
  for (int idx = t; idx < D_HID * D_OUTF; idx += 256){
    int k = idx >> 5, cc = idx & 31;
    sW[k * 64 + cc]      = W2[idx];
    sW[k * 64 + 32 + cc] = W3[idx];
  }
  __syncthreads();
  float a_s = half ? a3s[c] : a2s[c];
  float a_d = half ? a3d[c] : a2d[c];
  int nw = gridDim.x * 4;
  for (int node = blockIdx.x * 4 + wv; node < N_NODES; node += nw){
    float hv = h1a[(size_t)node * D_HID + lane];
    float acc = 0.f;
    #pragma unroll 16
    for (int k = 0; k < D_HID; ++k){
      float xk = __shfl(hv, k, 64);
      acc = fmaf(xk, sW[k * 64 + lane], acc);
    }
    h23[(size_t)node * 64 + lane] = acc;
    float vs = acc * a_s, vd = acc * a_d;
    for (int off = 16; off; off >>= 1){
      vs += __shfl_xor(vs, off, 64);
      vd += __shfl_xor(vd, off, 64);
    }
    if (c == 0){
      if (half){ es3[node] = vs; ed3[node] = vd; }
      else     { es2[node] = vs; ed2[node] = vd; }
    }
  }
}

// ---------------- layers 2&3 aggregation + relu + linear + alpha + var ----------------
__global__ __launch_bounds__(256) void k_agg23(const int* __restrict__ rowptr,
   const int* __restrict__ srcs, const int* __restrict__ eidx,
   const float* __restrict__ h23,
   const float* __restrict__ es2, const float* __restrict__ ed2,
   const float* __restrict__ es3, const float* __restrict__ ed3,
   const float* __restrict__ b2, const float* __restrict__ b3,
   const float* __restrict__ Wlin, const float* __restrict__ blin,
   float* __restrict__ mean_out, float* __restrict__ var_out,
   float* __restrict__ alpha_out){
  __shared__ float sWl[D_OUTF * D_OUTF];    // 4 KiB
  int t = threadIdx.x, lane = t & 63, wv = t >> 6;
  int half = lane >> 5, c = lane & 31;
  for (int idx = t; idx < D_OUTF * D_OUTF; idx += 256) sWl[idx] = Wlin[idx];
  __syncthreads();
  int node = blockIdx.x * 4 + wv;
  if (node >= N_NODES) return;
  int beg = rowptr[node], end = rowptr[node + 1];
  float ed2v = ed2[node];
  float ed3v = ed3[node];
  float edv  = half ? ed3v : ed2v;
  float e_self = leaky_relu(es3[node] + ed3v);   // layer-3 self loop
  float mloc = half ? e_self : -INFINITY;
  for (int i = beg + c; i < end; i += 32){
    int s = srcs[i];
    float esv = half ? es3[s] : es2[s];
    mloc = fmaxf(mloc, leaky_relu(esv + edv));
  }
  for (int off = 16; off; off >>= 1) mloc = fmaxf(mloc, __shfl_xor(mloc, off, 64));
  float m = mloc;                       // m2 in lower half, m3 in upper half
  float acc = 0.f, ssum = 0.f;
  for (int i = beg; i < end; ++i){
    int s = srcs[i];
    float esv = half ? es3[s] : es2[s];
    float p = __expf(leaky_relu(esv + edv) - m);
    ssum += p;
    acc = fmaf(p, h23[(size_t)s * 64 + lane], acc);   // coalesced 256B gather
  }
  if (half){
    float p = __expf(e_self - m);
    ssum += p;
    acc = fmaf(p, h23[(size_t)node * 64 + lane], acc);
  }
  float stot = ssum + 1e-16f;
  if (half){
    var_out[(size_t)node * D_OUTF + c] = acc / stot + b3[c];
  } else {
    float mean = acc / stot + b2[c];
    mean = mean > 0.f ? mean : 0.f;
    float o = blin[c];
    #pragma unroll 8
    for (int j = 0; j < D_OUTF; ++j){
      o = fmaf(__shfl(mean, j, 32), sWl[j * D_OUTF + c], o);
    }
    mean_out[(size_t)node * D_OUTF + c] = o;
    float inv = 1.f / stot;
    for (int i = beg + c; i < end; i += 32){
      int s = srcs[i];
      float p = __expf(leaky_relu(es2[s] + edv) - m);
      alpha_out[eidx[i]] = p * inv;
    }
  }
}

extern "C" void kernel_launch(void* const* d_in, const int* in_sizes, int n_in,
                              void* d_out, int out_size, void* d_ws, size_t ws_size,
                              hipStream_t stream) {
  const float* x   = (const float*)d_in[0];
  const int*   ei  = (const int*)d_in[1];
  const int*   src = ei;
  const int*   dst = ei + N_EDGES;
  const float* W1  = (const float*)d_in[2];
  const float* a1s = (const float*)d_in[3];
  const float* a1d = (const float*)d_in[4];
  const float* b1  = (const float*)d_in[5];
  const float* W2  = (const float*)d_in[6];
  const float* a2s = (const float*)d_in[7];
  const float* a2d = (const float*)d_in[8];
  const float* b2  = (const float*)d_in[9];
  const float* W3  = (const float*)d_in[10];
  const float* a3s = (const float*)d_in[11];
  const float* a3d = (const float*)d_in[12];
  const float* b3  = (const float*)d_in[13];
  const float* Wl  = (const float*)d_in[14];
  const float* bl  = (const float*)d_in[15];

  float* out       = (float*)d_out;
  float* mean_out  = out;
  float* var_out   = out + (size_t)N_NODES * D_OUTF;
  float* alpha_out = out + 2 * (size_t)N_NODES * D_OUTF;

  // workspace layout (ints first, then floats)
  int* deg     = (int*)d_ws;                 // N
  int* wcount  = deg + N_NODES;              // N
  int* rowptr  = wcount + N_NODES;           // N+1
  int* srcs    = rowptr + (N_NODES + 1);     // E
  int* eidx    = srcs + N_EDGES;             // E
  float* h1    = (float*)(eidx + N_EDGES);   // N*64  (reused as h23)
  float* h1act = h1 + (size_t)N_NODES * 64;  // N*64
  float* es1   = h1act + (size_t)N_NODES * 64;
  float* ed1   = es1 + N_NODES;
  float* es2   = ed1 + N_NODES;
  float* ed2   = es2 + N_NODES;
  float* es3   = ed2 + N_NODES;
  float* ed3   = es3 + N_NODES;
  float* h23   = h1;                         // reuse (h1 dead after k_agg1)

  hipMemsetAsync(deg, 0, 2 * (size_t)N_NODES * sizeof(int), stream);

  k_deg <<<(N_EDGES + 255) / 256, 256, 0, stream>>>(dst, deg);
  k_scan<<<1, 1024, 0, stream>>>(deg, rowptr);
  k_fill<<<(N_EDGES + 255) / 256, 256, 0, stream>>>(src, dst, rowptr, wcount, srcs, eidx);

  k_gemm1<<<512, 256, 0, stream>>>(x, W1, a1s, a1d, h1, es1, ed1);
  k_agg1 <<<(N_NODES + 3) / 4, 256, 0, stream>>>(rowptr, srcs, h1, es1, ed1, b1, h1act);
  k_gemm23<<<1024, 256, 0, stream>>>(h1act, W2, W3, a2s, a2d, a3s, a3d,
                                     h23, es2, ed2, es3, ed3);
  k_agg23<<<(N_NODES + 3) / 4, 256, 0, stream>>>(rowptr, srcs, eidx, h23,
                                                 es2, ed2, es3, ed3, b2, b3, Wl, bl,
                                                 mean_out, var_out, alpha_out);
}

// Round 2
// 428.435 us; speedup vs baseline: 1.1516x; 1.1516x over previous
//
#include <hip/hip_runtime.h>
#include <math.h>

#define N_NODES 50000
#define N_EDGES 800000
#define D_INF   256
#define D_HID   64
#define D_OUTF  32
#define LEAKY   0.2f

#define MT 64     // gemm1 M-tile rows
#define KB 16     // gemm1 K-step

__device__ __forceinline__ float leaky_relu(float x){ return x >= 0.f ? x : LEAKY * x; }

// ---------------- CSR build ----------------
__global__ void k_deg(const int* __restrict__ dst, int* __restrict__ deg){
  int i = blockIdx.x * blockDim.x + threadIdx.x;
  if (i < N_EDGES) atomicAdd(&deg[dst[i]], 1);
}

__global__ void k_scan(const int* __restrict__ deg, int* __restrict__ rowptr){
  __shared__ int wsum[16];
  __shared__ int s_carry;
  int t = threadIdx.x, lane = t & 63, wv = t >> 6;
  if (t == 0){ s_carry = 0; rowptr[0] = 0; }
  __syncthreads();
  for (int base = 0; base < N_NODES; base += 1024){
    int i = base + t;
    int x = (i < N_NODES) ? deg[i] : 0;
    for (int off = 1; off < 64; off <<= 1){
      int y = __shfl_up(x, off, 64);
      if (lane >= off) x += y;
    }
    if (lane == 63) wsum[wv] = x;
    __syncthreads();
    if (t < 16){
      int w = wsum[t];
      for (int off = 1; off < 16; off <<= 1){
        int y = __shfl_up(w, off, 64);
        if (t >= off) w += y;
      }
      wsum[t] = w;
    }
    __syncthreads();
    int waveoff = (wv == 0) ? 0 : wsum[wv - 1];
    int incl = s_carry + waveoff + x;
    if (i < N_NODES) rowptr[i + 1] = incl;
    __syncthreads();
    if (t == 0) s_carry += wsum[15];
    __syncthreads();
  }
}

__global__ void k_fill(const int* __restrict__ src, const int* __restrict__ dst,
                       const int* __restrict__ rowptr, int* __restrict__ wcount,
                       int* __restrict__ srcs, int* __restrict__ eidx){
  int i = blockIdx.x * blockDim.x + threadIdx.x;
  if (i < N_EDGES){
    int d = dst[i];
    int pos = rowptr[d] + atomicAdd(&wcount[d], 1);
    srcs[pos] = src[i];
    eidx[pos] = i;
  }
}

// ---------------- layer 1 GEMM: h1 = x@W1 (tiled), es1/ed1 dots ----------------
__global__ __launch_bounds__(256) void k_gemm1(const float* __restrict__ x,
        const float* __restrict__ W1,
        const float* __restrict__ a_src, const float* __restrict__ a_dst,
        float* __restrict__ h1, float* __restrict__ es, float* __restrict__ ed){
  __shared__ float xs[2][MT][KB + 4];     // pad 4 -> float4-aligned rows, 10.2 KiB
  __shared__ float ws[2][KB][D_HID];      // 8 KiB
  const int tid = threadIdx.x;
  const int tc  = tid & 15;               // col group: cols tc*4..tc*4+3
  const int tr  = tid >> 4;               // row group: rows tr*4..tr*4+3
  const int row0 = blockIdx.x * MT;

  // loader mapping
  const int lxr = tid >> 2;               // x-tile row 0..63
  const int lxp = (tid & 3) << 2;         // x-tile col 0,4,8,12
  const int gxrow = row0 + lxr;
  const bool xok = gxrow < N_NODES;
  const float* xbase = x + (size_t)gxrow * D_INF + lxp;
  const int lwr = tid >> 4;               // w-tile row 0..15
  const int lwp = (tid & 15) << 2;        // w-tile col
  const float* wbase = W1 + lwr * D_HID + lwp;

  float4 xv = xok ? *(const float4*)xbase : make_float4(0.f,0.f,0.f,0.f);
  float4 wv = *(const float4*)wbase;
  *(float4*)&xs[0][lxr][lxp] = xv;
  *(float4*)&ws[0][lwr][lwp] = wv;
  __syncthreads();

  float acc[4][4] = {};
  int b = 0;
  #pragma unroll 1
  for (int ks = 0; ks < D_INF / KB; ++ks){
    if (ks < D_INF / KB - 1){
      xv = xok ? *(const float4*)(xbase + (ks + 1) * KB) : make_float4(0.f,0.f,0.f,0.f);
      wv = *(const float4*)(wbase + (size_t)(ks + 1) * KB * D_HID);
    }
    #pragma unroll
    for (int k4 = 0; k4 < KB / 4; ++k4){
      float4 xr4[4];
      #pragma unroll
      for (int r = 0; r < 4; ++r)
        xr4[r] = *(float4*)&xs[b][(tr << 2) + r][k4 << 2];
      #pragma unroll
      for (int j = 0; j < 4; ++j){
        float4 w4 = *(float4*)&ws[b][(k4 << 2) + j][tc << 2];
        #pragma unroll
        for (int r = 0; r < 4; ++r){
          float xk = (j == 0) ? xr4[r].x : (j == 1) ? xr4[r].y : (j == 2) ? xr4[r].z : xr4[r].w;
          acc[r][0] = fmaf(xk, w4.x, acc[r][0]);
          acc[r][1] = fmaf(xk, w4.y, acc[r][1]);
          acc[r][2] = fmaf(xk, w4.z, acc[r][2]);
          acc[r][3] = fmaf(xk, w4.w, acc[r][3]);
        }
      }
    }
    if (ks < D_INF / KB - 1){
      *(float4*)&xs[b ^ 1][lxr][lxp] = xv;
      *(float4*)&ws[b ^ 1][lwr][lwp] = wv;
    }
    __syncthreads();
    b ^= 1;
  }

  // epilogue: store h1, reduce attention dots across the 16 col-threads
  float as0 = a_src[tc << 2], as1 = a_src[(tc << 2) + 1],
        as2 = a_src[(tc << 2) + 2], as3 = a_src[(tc << 2) + 3];
  float ad0 = a_dst[tc << 2], ad1 = a_dst[(tc << 2) + 1],
        ad2 = a_dst[(tc << 2) + 2], ad3 = a_dst[(tc << 2) + 3];
  #pragma unroll
  for (int r = 0; r < 4; ++r){
    int row = row0 + (tr << 2) + r;
    float ps = acc[r][0]*as0 + acc[r][1]*as1 + acc[r][2]*as2 + acc[r][3]*as3;
    float pd = acc[r][0]*ad0 + acc[r][1]*ad1 + acc[r][2]*ad2 + acc[r][3]*ad3;
    #pragma unroll
    for (int off = 1; off < 16; off <<= 1){
      ps += __shfl_xor(ps, off, 64);
      pd += __shfl_xor(pd, off, 64);
    }
    if (row < N_NODES){
      *(float4*)&h1[(size_t)row * D_HID + (tc << 2)] =
          make_float4(acc[r][0], acc[r][1], acc[r][2], acc[r][3]);
      if (tc == 0){ es[row] = ps; ed[row] = pd; }
    }
  }
}

// ---------------- layer 1 aggregation + bias + ELU (no-max softmax) ----------------
__global__ __launch_bounds__(256) void k_agg1(const int* __restrict__ rowptr,
      const int* __restrict__ srcs,
      const float* __restrict__ h1, const float* __restrict__ es,
      const float* __restrict__ ed, const float* __restrict__ b1,
      float* __restrict__ h1act){
  int t = threadIdx.x, lane = t & 63, wv = t >> 6;
  int node = blockIdx.x * 4 + wv;
  if (node >= N_NODES) return;
  int beg = rowptr[node], end = rowptr[node + 1];
  float edv = ed[node];
  float acc = 0.f, ssum = 0.f;
  for (int i = beg; i < end; ++i){
    int s = srcs[i];                         // wave-uniform load
    float p = __expf(leaky_relu(es[s] + edv));
    ssum += p;
    acc = fmaf(p, h1[(size_t)s * D_HID + lane], acc);   // coalesced 256B gather
  }
  float o = acc / (ssum + 1e-16f) + b1[lane];
  h1act[(size_t)node * D_HID + lane] = o > 0.f ? o : expm1f(o);
}

// ---------------- layers 2&3 GEMM (interleaved h23) ----------------
__global__ __launch_bounds__(256) void k_gemm23(const float* __restrict__ h1a,
   const float* __restrict__ W2, const float* __restrict__ W3,
   const float* __restrict__ a2s, const float* __restrict__ a2d,
   const float* __restrict__ a3s, const float* __restrict__ a3d,
   float* __restrict__ h23, float* __restrict__ es2, float* __restrict__ ed2,
   float* __restrict__ es3, float* __restrict__ ed3){
  __shared__ float sW[D_HID * 64];          // [k][half*32+c], 16 KiB
  int t = threadIdx.x, lane = t & 63, wv = t >> 6;
  int half = lane >> 5, c = lane & 31;
  for (int idx = t; idx < D_HID * D_OUTF; idx += 256){
    int k = idx >> 5, cc = idx & 31;
    sW[k * 64 + cc]      = W2[idx];
    sW[k * 64 + 32 + cc] = W3[idx];
  }
  __syncthreads();
  float a_s = half ? a3s[c] : a2s[c];
  float a_d = half ? a3d[c] : a2d[c];
  int nw = gridDim.x * 4;
  for (int node = blockIdx.x * 4 + wv; node < N_NODES; node += nw){
    float hv = h1a[(size_t)node * D_HID + lane];
    float acc = 0.f;
    #pragma unroll 16
    for (int k = 0; k < D_HID; ++k){
      float xk = __shfl(hv, k, 64);
      acc = fmaf(xk, sW[k * 64 + lane], acc);
    }
    h23[(size_t)node * 64 + lane] = acc;
    float vs = acc * a_s, vd = acc * a_d;
    for (int off = 16; off; off >>= 1){
      vs += __shfl_xor(vs, off, 64);
      vd += __shfl_xor(vd, off, 64);
    }
    if (c == 0){
      if (half){ es3[node] = vs; ed3[node] = vd; }
      else     { es2[node] = vs; ed2[node] = vd; }
    }
  }
}

// ---------------- layers 2&3 aggregation (no-max) + relu + linear + alpha + var --------
__global__ __launch_bounds__(256) void k_agg23(const int* __restrict__ rowptr,
   const int* __restrict__ srcs, const int* __restrict__ eidx,
   const float* __restrict__ h23,
   const float* __restrict__ es2, const float* __restrict__ ed2,
   const float* __restrict__ es3, const float* __restrict__ ed3,
   const float* __restrict__ b2, const float* __restrict__ b3,
   const float* __restrict__ Wlin, const float* __restrict__ blin,
   float* __restrict__ mean_out, float* __restrict__ var_out,
   float* __restrict__ alpha_out){
  __shared__ float sWl[D_OUTF * D_OUTF];    // 4 KiB
  int t = threadIdx.x, lane = t & 63, wv = t >> 6;
  int half = lane >> 5, c = lane & 31;
  for (int idx = t; idx < D_OUTF * D_OUTF; idx += 256) sWl[idx] = Wlin[idx];
  __syncthreads();
  int node = blockIdx.x * 4 + wv;
  if (node >= N_NODES) return;
  int beg = rowptr[node], end = rowptr[node + 1];
  float ed2v = ed2[node];
  float ed3v = ed3[node];
  float edv  = half ? ed3v : ed2v;
  float acc = 0.f, ssum = 0.f;
  for (int i = beg; i < end; ++i){
    int s = srcs[i];
    float esv = half ? es3[s] : es2[s];
    float p = __expf(leaky_relu(esv + edv));
    ssum += p;
    acc = fmaf(p, h23[(size_t)s * 64 + lane], acc);   // coalesced 256B gather
  }
  if (half){  // layer-3 self loop
    float p = __expf(leaky_relu(es3[node] + ed3v));
    ssum += p;
    acc = fmaf(p, h23[(size_t)node * 64 + lane], acc);
  }
  float stot = ssum + 1e-16f;
  if (half){
    var_out[(size_t)node * D_OUTF + c] = acc / stot + b3[c];
  } else {
    float mean = acc / stot + b2[c];
    mean = mean > 0.f ? mean : 0.f;
    float o = blin[c];
    #pragma unroll 8
    for (int j = 0; j < D_OUTF; ++j){
      o = fmaf(__shfl(mean, j, 32), sWl[j * D_OUTF + c], o);
    }
    mean_out[(size_t)node * D_OUTF + c] = o;
    float inv = 1.f / stot;
    for (int i = beg + c; i < end; i += 32){
      int s = srcs[i];
      float p = __expf(leaky_relu(es2[s] + edv));
      alpha_out[eidx[i]] = p * inv;
    }
  }
}

extern "C" void kernel_launch(void* const* d_in, const int* in_sizes, int n_in,
                              void* d_out, int out_size, void* d_ws, size_t ws_size,
                              hipStream_t stream) {
  const float* x   = (const float*)d_in[0];
  const int*   ei  = (const int*)d_in[1];
  const int*   src = ei;
  const int*   dst = ei + N_EDGES;
  const float* W1  = (const float*)d_in[2];
  const float* a1s = (const float*)d_in[3];
  const float* a1d = (const float*)d_in[4];
  const float* b1  = (const float*)d_in[5];
  const float* W2  = (const float*)d_in[6];
  const float* a2s = (const float*)d_in[7];
  const float* a2d = (const float*)d_in[8];
  const float* b2  = (const float*)d_in[9];
  const float* W3  = (const float*)d_in[10];
  const float* a3s = (const float*)d_in[11];
  const float* a3d = (const float*)d_in[12];
  const float* b3  = (const float*)d_in[13];
  const float* Wl  = (const float*)d_in[14];
  const float* bl  = (const float*)d_in[15];

  float* out       = (float*)d_out;
  float* mean_out  = out;
  float* var_out   = out + (size_t)N_NODES * D_OUTF;
  float* alpha_out = out + 2 * (size_t)N_NODES * D_OUTF;

  int* deg     = (int*)d_ws;                 // N
  int* wcount  = deg + N_NODES;              // N
  int* rowptr  = wcount + N_NODES;           // N+1
  int* srcs    = rowptr + (N_NODES + 1);     // E
  int* eidx    = srcs + N_EDGES;             // E
  float* h1    = (float*)(eidx + N_EDGES);   // N*64  (reused as h23)
  float* h1act = h1 + (size_t)N_NODES * 64;  // N*64
  float* es1   = h1act + (size_t)N_NODES * 64;
  float* ed1   = es1 + N_NODES;
  float* es2   = ed1 + N_NODES;
  float* ed2   = es2 + N_NODES;
  float* es3   = ed2 + N_NODES;
  float* ed3   = es3 + N_NODES;
  float* h23   = h1;                         // reuse (h1 dead after k_agg1)

  hipMemsetAsync(deg, 0, 2 * (size_t)N_NODES * sizeof(int), stream);

  k_deg <<<(N_EDGES + 255) / 256, 256, 0, stream>>>(dst, deg);
  k_scan<<<1, 1024, 0, stream>>>(deg, rowptr);
  k_fill<<<(N_EDGES + 255) / 256, 256, 0, stream>>>(src, dst, rowptr, wcount, srcs, eidx);

  k_gemm1<<<(N_NODES + MT - 1) / MT, 256, 0, stream>>>(x, W1, a1s, a1d, h1, es1, ed1);
  k_agg1 <<<(N_NODES + 3) / 4, 256, 0, stream>>>(rowptr, srcs, h1, es1, ed1, b1, h1act);
  k_gemm23<<<1024, 256, 0, stream>>>(h1act, W2, W3, a2s, a2d, a3s, a3d,
                                     h23, es2, ed2, es3, ed3);
  k_agg23<<<(N_NODES + 3) / 4, 256, 0, stream>>>(rowptr, srcs, eidx, h23,
                                                 es2, ed2, es3, ed3, b2, b3, Wl, bl,
                                                 mean_out, var_out, alpha_out);
}

// Round 3
// 320.782 us; speedup vs baseline: 1.5381x; 1.3356x over previous
//
#include <hip/hip_runtime.h>
#include <math.h>

#define N_NODES 50000
#define N_EDGES 800000
#define D_INF   256
#define D_HID   64
#define D_OUTF  32
#define LEAKY   0.2f

#define MT 64     // gemm1 M-tile rows
#define KB 16     // gemm1 K-step

__device__ __forceinline__ float leaky_relu(float x){ return x >= 0.f ? x : LEAKY * x; }

// ---------------- CSR build ----------------
__global__ void k_deg(const int* __restrict__ dst, int* __restrict__ deg){
  int i = blockIdx.x * blockDim.x + threadIdx.x;
  if (i < N_EDGES) atomicAdd(&deg[dst[i]], 1);
}

__global__ void k_scan(const int* __restrict__ deg, int* __restrict__ rowptr){
  __shared__ int wsum[16];
  __shared__ int s_carry;
  int t = threadIdx.x, lane = t & 63, wv = t >> 6;
  if (t == 0){ s_carry = 0; rowptr[0] = 0; }
  __syncthreads();
  for (int base = 0; base < N_NODES; base += 1024){
    int i = base + t;
    int x = (i < N_NODES) ? deg[i] : 0;
    for (int off = 1; off < 64; off <<= 1){
      int y = __shfl_up(x, off, 64);
      if (lane >= off) x += y;
    }
    if (lane == 63) wsum[wv] = x;
    __syncthreads();
    if (t < 16){
      int w = wsum[t];
      for (int off = 1; off < 16; off <<= 1){
        int y = __shfl_up(w, off, 64);
        if (t >= off) w += y;
      }
      wsum[t] = w;
    }
    __syncthreads();
    int waveoff = (wv == 0) ? 0 : wsum[wv - 1];
    int incl = s_carry + waveoff + x;
    if (i < N_NODES) rowptr[i + 1] = incl;
    __syncthreads();
    if (t == 0) s_carry += wsum[15];
    __syncthreads();
  }
}

__global__ void k_fill(const int* __restrict__ src, const int* __restrict__ dst,
                       const int* __restrict__ rowptr, int* __restrict__ wcount,
                       int* __restrict__ srcs){
  int i = blockIdx.x * blockDim.x + threadIdx.x;
  if (i < N_EDGES){
    int d = dst[i];
    int pos = rowptr[d] + atomicAdd(&wcount[d], 1);
    srcs[pos] = src[i];
  }
}

// ---------------- layer 1 GEMM: h1 = x@W1 (tiled), es1/ed1 dots ----------------
__global__ __launch_bounds__(256) void k_gemm1(const float* __restrict__ x,
        const float* __restrict__ W1,
        const float* __restrict__ a_src, const float* __restrict__ a_dst,
        float* __restrict__ h1, float* __restrict__ es, float* __restrict__ ed){
  __shared__ float xs[2][MT][KB + 4];
  __shared__ float ws[2][KB][D_HID];
  const int tid = threadIdx.x;
  const int tc  = tid & 15;
  const int tr  = tid >> 4;
  const int row0 = blockIdx.x * MT;

  const int lxr = tid >> 2;
  const int lxp = (tid & 3) << 2;
  const int gxrow = row0 + lxr;
  const bool xok = gxrow < N_NODES;
  const float* xbase = x + (size_t)gxrow * D_INF + lxp;
  const int lwr = tid >> 4;
  const int lwp = (tid & 15) << 2;
  const float* wbase = W1 + lwr * D_HID + lwp;

  float4 xv = xok ? *(const float4*)xbase : make_float4(0.f,0.f,0.f,0.f);
  float4 wv = *(const float4*)wbase;
  *(float4*)&xs[0][lxr][lxp] = xv;
  *(float4*)&ws[0][lwr][lwp] = wv;
  __syncthreads();

  float acc[4][4] = {};
  int b = 0;
  #pragma unroll 1
  for (int ks = 0; ks < D_INF / KB; ++ks){
    if (ks < D_INF / KB - 1){
      xv = xok ? *(const float4*)(xbase + (ks + 1) * KB) : make_float4(0.f,0.f,0.f,0.f);
      wv = *(const float4*)(wbase + (size_t)(ks + 1) * KB * D_HID);
    }
    #pragma unroll
    for (int k4 = 0; k4 < KB / 4; ++k4){
      float4 xr4[4];
      #pragma unroll
      for (int r = 0; r < 4; ++r)
        xr4[r] = *(float4*)&xs[b][(tr << 2) + r][k4 << 2];
      #pragma unroll
      for (int j = 0; j < 4; ++j){
        float4 w4 = *(float4*)&ws[b][(k4 << 2) + j][tc << 2];
        #pragma unroll
        for (int r = 0; r < 4; ++r){
          float xk = (j == 0) ? xr4[r].x : (j == 1) ? xr4[r].y : (j == 2) ? xr4[r].z : xr4[r].w;
          acc[r][0] = fmaf(xk, w4.x, acc[r][0]);
          acc[r][1] = fmaf(xk, w4.y, acc[r][1]);
          acc[r][2] = fmaf(xk, w4.z, acc[r][2]);
          acc[r][3] = fmaf(xk, w4.w, acc[r][3]);
        }
      }
    }
    if (ks < D_INF / KB - 1){
      *(float4*)&xs[b ^ 1][lxr][lxp] = xv;
      *(float4*)&ws[b ^ 1][lwr][lwp] = wv;
    }
    __syncthreads();
    b ^= 1;
  }

  float as0 = a_src[tc << 2], as1 = a_src[(tc << 2) + 1],
        as2 = a_src[(tc << 2) + 2], as3 = a_src[(tc << 2) + 3];
  float ad0 = a_dst[tc << 2], ad1 = a_dst[(tc << 2) + 1],
        ad2 = a_dst[(tc << 2) + 2], ad3 = a_dst[(tc << 2) + 3];
  #pragma unroll
  for (int r = 0; r < 4; ++r){
    int row = row0 + (tr << 2) + r;
    float ps = acc[r][0]*as0 + acc[r][1]*as1 + acc[r][2]*as2 + acc[r][3]*as3;
    float pd = acc[r][0]*ad0 + acc[r][1]*ad1 + acc[r][2]*ad2 + acc[r][3]*ad3;
    #pragma unroll
    for (int off = 1; off < 16; off <<= 1){
      ps += __shfl_xor(ps, off, 64);
      pd += __shfl_xor(pd, off, 64);
    }
    if (row < N_NODES){
      *(float4*)&h1[(size_t)row * D_HID + (tc << 2)] =
          make_float4(acc[r][0], acc[r][1], acc[r][2], acc[r][3]);
      if (tc == 0){ es[row] = ps; ed[row] = pd; }
    }
  }
}

// ------- layer 1 aggregation + bias + ELU + FUSED gemm2/3 + attention dots -------
__global__ __launch_bounds__(256) void k_agg1(const int* __restrict__ rowptr,
      const int* __restrict__ srcs,
      const float* __restrict__ h1, const float* __restrict__ es,
      const float* __restrict__ ed, const float* __restrict__ b1,
      const float* __restrict__ W2, const float* __restrict__ W3,
      const float* __restrict__ a2s, const float* __restrict__ a2d,
      const float* __restrict__ a3s, const float* __restrict__ a3d,
      float* __restrict__ h23, float* __restrict__ es2, float* __restrict__ ed2,
      float* __restrict__ es3, float* __restrict__ ed3){
  __shared__ float sW[D_HID * 64];          // [k][half*32+c], 16 KiB
  int t = threadIdx.x, lane = t & 63, wv = t >> 6;
  int half = lane >> 5, c = lane & 31;
  for (int idx = t; idx < D_HID * D_OUTF; idx += 256){
    int k = idx >> 5, cc = idx & 31;
    sW[k * 64 + cc]      = W2[idx];
    sW[k * 64 + 32 + cc] = W3[idx];
  }
  __syncthreads();

  int node = blockIdx.x * 4 + wv;           // N divisible by 4 -> always valid
  int beg = rowptr[node], end = rowptr[node + 1];
  float edv = ed[node];
  float a0 = 0.f, a1 = 0.f, a2 = 0.f, a3 = 0.f, ss = 0.f;
  int i = beg;
  for (; i + 3 < end; i += 4){
    int s0 = srcs[i], s1 = srcs[i+1], s2 = srcs[i+2], s3 = srcs[i+3];
    float v0 = h1[(size_t)s0 * D_HID + lane];
    float v1 = h1[(size_t)s1 * D_HID + lane];
    float v2 = h1[(size_t)s2 * D_HID + lane];
    float v3 = h1[(size_t)s3 * D_HID + lane];
    float p0 = __expf(leaky_relu(es[s0] + edv));
    float p1 = __expf(leaky_relu(es[s1] + edv));
    float p2 = __expf(leaky_relu(es[s2] + edv));
    float p3 = __expf(leaky_relu(es[s3] + edv));
    ss += (p0 + p1) + (p2 + p3);
    a0 = fmaf(p0, v0, a0); a1 = fmaf(p1, v1, a1);
    a2 = fmaf(p2, v2, a2); a3 = fmaf(p3, v3, a3);
  }
  for (; i < end; ++i){
    int s = srcs[i];
    float v = h1[(size_t)s * D_HID + lane];
    float p = __expf(leaky_relu(es[s] + edv));
    ss += p;
    a0 = fmaf(p, v, a0);
  }
  float acc = (a0 + a1) + (a2 + a3);
  float o = acc / (ss + 1e-16f) + b1[lane];
  float hv = o > 0.f ? o : expm1f(o);       // h1act (node, lane), register-only

  // fused layer-2/3 linear: h23 row = h1act_row @ [W2 | W3]
  float a_s = half ? a3s[c] : a2s[c];
  float a_d = half ? a3d[c] : a2d[c];
  float g = 0.f;
  #pragma unroll
  for (int k = 0; k < D_HID; ++k){
    float xk = __shfl(hv, k, 64);
    g = fmaf(xk, sW[k * 64 + lane], g);
  }
  h23[(size_t)node * 64 + lane] = g;
  float vs = g * a_s, vd = g * a_d;
  #pragma unroll
  for (int off = 16; off; off >>= 1){
    vs += __shfl_xor(vs, off, 64);
    vd += __shfl_xor(vd, off, 64);
  }
  if (c == 0){
    if (half){ es3[node] = vs; ed3[node] = vd; }
    else     { es2[node] = vs; ed2[node] = vd; }
  }
}

// ------- layers 2&3 aggregation + relu + linear + var; stores inv_s2 -------
__global__ __launch_bounds__(256) void k_agg23(const int* __restrict__ rowptr,
   const int* __restrict__ srcs,
   const float* __restrict__ h23,
   const float* __restrict__ es2, const float* __restrict__ ed2,
   const float* __restrict__ es3, const float* __restrict__ ed3,
   const float* __restrict__ b2, const float* __restrict__ b3,
   const float* __restrict__ Wlin, const float* __restrict__ blin,
   float* __restrict__ mean_out, float* __restrict__ var_out,
   float* __restrict__ inv_s2){
  __shared__ float sWl[D_OUTF * D_OUTF];
  int t = threadIdx.x, lane = t & 63, wv = t >> 6;
  int half = lane >> 5, c = lane & 31;
  for (int idx = t; idx < D_OUTF * D_OUTF; idx += 256) sWl[idx] = Wlin[idx];
  __syncthreads();

  int node = blockIdx.x * 4 + wv;
  int beg = rowptr[node], end = rowptr[node + 1];
  const float* esT = half ? es3 : es2;
  float edv = half ? ed3[node] : ed2[node];
  float a0 = 0.f, a1 = 0.f, a2 = 0.f, a3 = 0.f, ss = 0.f;
  int i = beg;
  for (; i + 3 < end; i += 4){
    int s0 = srcs[i], s1 = srcs[i+1], s2 = srcs[i+2], s3 = srcs[i+3];
    float v0 = h23[(size_t)s0 * 64 + lane];
    float v1 = h23[(size_t)s1 * 64 + lane];
    float v2 = h23[(size_t)s2 * 64 + lane];
    float v3 = h23[(size_t)s3 * 64 + lane];
    float p0 = __expf(leaky_relu(esT[s0] + edv));
    float p1 = __expf(leaky_relu(esT[s1] + edv));
    float p2 = __expf(leaky_relu(esT[s2] + edv));
    float p3 = __expf(leaky_relu(esT[s3] + edv));
    ss += (p0 + p1) + (p2 + p3);
    a0 = fmaf(p0, v0, a0); a1 = fmaf(p1, v1, a1);
    a2 = fmaf(p2, v2, a2); a3 = fmaf(p3, v3, a3);
  }
  for (; i < end; ++i){
    int s = srcs[i];
    float v = h23[(size_t)s * 64 + lane];
    float p = __expf(leaky_relu(esT[s] + edv));
    ss += p;
    a0 = fmaf(p, v, a0);
  }
  if (half){  // layer-3 self loop
    float p = __expf(leaky_relu(es3[node] + ed3[node]));
    ss += p;
    a0 = fmaf(p, h23[(size_t)node * 64 + lane], a0);
  }
  float acc = (a0 + a1) + (a2 + a3);
  float stot = ss + 1e-16f;
  if (half){
    var_out[(size_t)node * D_OUTF + c] = acc / stot + b3[c];
  } else {
    float mean = acc / stot + b2[c];
    mean = mean > 0.f ? mean : 0.f;
    float o = blin[c];
    #pragma unroll
    for (int j = 0; j < D_OUTF; ++j){
      o = fmaf(__shfl(mean, j, 32), sWl[j * D_OUTF + c], o);
    }
    mean_out[(size_t)node * D_OUTF + c] = o;
    if (c == 0) inv_s2[node] = 1.f / stot;
  }
}

// ------- alpha: flat edge-parallel, coalesced write -------
__global__ __launch_bounds__(256) void k_alpha(const int* __restrict__ src,
    const int* __restrict__ dst,
    const float* __restrict__ es2, const float* __restrict__ ed2,
    const float* __restrict__ inv_s2, float* __restrict__ alpha_out){
  int e = blockIdx.x * blockDim.x + threadIdx.x;
  if (e < N_EDGES){
    int s = src[e], d = dst[e];
    alpha_out[e] = __expf(leaky_relu(es2[s] + ed2[d])) * inv_s2[d];
  }
}

extern "C" void kernel_launch(void* const* d_in, const int* in_sizes, int n_in,
                              void* d_out, int out_size, void* d_ws, size_t ws_size,
                              hipStream_t stream) {
  const float* x   = (const float*)d_in[0];
  const int*   ei  = (const int*)d_in[1];
  const int*   src = ei;
  const int*   dst = ei + N_EDGES;
  const float* W1  = (const float*)d_in[2];
  const float* a1s = (const float*)d_in[3];
  const float* a1d = (const float*)d_in[4];
  const float* b1  = (const float*)d_in[5];
  const float* W2  = (const float*)d_in[6];
  const float* a2s = (const float*)d_in[7];
  const float* a2d = (const float*)d_in[8];
  const float* b2  = (const float*)d_in[9];
  const float* W3  = (const float*)d_in[10];
  const float* a3s = (const float*)d_in[11];
  const float* a3d = (const float*)d_in[12];
  const float* b3  = (const float*)d_in[13];
  const float* Wl  = (const float*)d_in[14];
  const float* bl  = (const float*)d_in[15];

  float* out       = (float*)d_out;
  float* mean_out  = out;
  float* var_out   = out + (size_t)N_NODES * D_OUTF;
  float* alpha_out = out + 2 * (size_t)N_NODES * D_OUTF;

  int* deg     = (int*)d_ws;                 // N
  int* wcount  = deg + N_NODES;              // N
  int* rowptr  = wcount + N_NODES;           // N+1
  int* srcs    = rowptr + (N_NODES + 1);     // E
  float* h1    = (float*)(srcs + N_EDGES);   // N*64
  float* h23   = h1 + (size_t)N_NODES * 64;  // N*64
  float* es1   = h23 + (size_t)N_NODES * 64;
  float* ed1   = es1 + N_NODES;
  float* es2   = ed1 + N_NODES;
  float* ed2   = es2 + N_NODES;
  float* es3   = ed2 + N_NODES;
  float* ed3   = es3 + N_NODES;
  float* invs2 = ed3 + N_NODES;

  hipMemsetAsync(deg, 0, 2 * (size_t)N_NODES * sizeof(int), stream);

  k_deg <<<(N_EDGES + 255) / 256, 256, 0, stream>>>(dst, deg);
  k_scan<<<1, 1024, 0, stream>>>(deg, rowptr);
  k_fill<<<(N_EDGES + 255) / 256, 256, 0, stream>>>(src, dst, rowptr, wcount, srcs);

  k_gemm1<<<(N_NODES + MT - 1) / MT, 256, 0, stream>>>(x, W1, a1s, a1d, h1, es1, ed1);
  k_agg1 <<<N_NODES / 4, 256, 0, stream>>>(rowptr, srcs, h1, es1, ed1, b1,
                                           W2, W3, a2s, a2d, a3s, a3d,
                                           h23, es2, ed2, es3, ed3);
  k_agg23<<<N_NODES / 4, 256, 0, stream>>>(rowptr, srcs, h23,
                                           es2, ed2, es3, ed3, b2, b3, Wl, bl,
                                           mean_out, var_out, invs2);
  k_alpha<<<(N_EDGES + 255) / 256, 256, 0, stream>>>(src, dst, es2, ed2, invs2, alpha_out);
}

// Round 4
// 304.781 us; speedup vs baseline: 1.6189x; 1.0525x over previous
//
#include <hip/hip_runtime.h>
#include <hip/hip_fp16.h>
#include <math.h>

#define N_NODES 50000
#define N_EDGES 800000
#define D_INF   256
#define D_HID   64
#define D_OUTF  32
#define LEAKY   0.2f

#define MT 64     // gemm1 M-tile rows
#define KB 16     // gemm1 K-step

__device__ __forceinline__ float leaky_relu(float x){ return x >= 0.f ? x : LEAKY * x; }

union H4 { __half2 h[2]; float2 f; };

// ---------------- CSR build ----------------
__global__ void k_deg(const int* __restrict__ dst, int* __restrict__ deg){
  int i = blockIdx.x * blockDim.x + threadIdx.x;
  if (i < N_EDGES) atomicAdd(&deg[dst[i]], 1);
}

__global__ void k_scan(const int* __restrict__ deg, int* __restrict__ rowptr){
  __shared__ int wsum[16];
  __shared__ int s_carry;
  int t = threadIdx.x, lane = t & 63, wv = t >> 6;
  if (t == 0){ s_carry = 0; rowptr[0] = 0; }
  __syncthreads();
  for (int base = 0; base < N_NODES; base += 1024){
    int i = base + t;
    int x = (i < N_NODES) ? deg[i] : 0;
    for (int off = 1; off < 64; off <<= 1){
      int y = __shfl_up(x, off, 64);
      if (lane >= off) x += y;
    }
    if (lane == 63) wsum[wv] = x;
    __syncthreads();
    if (t < 16){
      int w = wsum[t];
      for (int off = 1; off < 16; off <<= 1){
        int y = __shfl_up(w, off, 64);
        if (t >= off) w += y;
      }
      wsum[t] = w;
    }
    __syncthreads();
    int waveoff = (wv == 0) ? 0 : wsum[wv - 1];
    int incl = s_carry + waveoff + x;
    if (i < N_NODES) rowptr[i + 1] = incl;
    __syncthreads();
    if (t == 0) s_carry += wsum[15];
    __syncthreads();
  }
}

__global__ void k_fill(const int* __restrict__ src, const int* __restrict__ dst,
                       const int* __restrict__ rowptr, int* __restrict__ wcount,
                       int* __restrict__ srcs){
  int i = blockIdx.x * blockDim.x + threadIdx.x;
  if (i < N_EDGES){
    int d = dst[i];
    int pos = rowptr[d] + atomicAdd(&wcount[d], 1);
    srcs[pos] = src[i];
  }
}

// ---------------- layer 1 GEMM: h1 = x@W1 (tiled, fp16 out), es1/ed1 dots ----------------
__global__ __launch_bounds__(256) void k_gemm1(const float* __restrict__ x,
        const float* __restrict__ W1,
        const float* __restrict__ a_src, const float* __restrict__ a_dst,
        __half* __restrict__ h1h, float* __restrict__ es, float* __restrict__ ed){
  __shared__ float xs[2][MT][KB + 4];
  __shared__ float ws[2][KB][D_HID];
  const int tid = threadIdx.x;
  const int tc  = tid & 15;
  const int tr  = tid >> 4;
  const int row0 = blockIdx.x * MT;

  const int lxr = tid >> 2;
  const int lxp = (tid & 3) << 2;
  const int gxrow = row0 + lxr;
  const bool xok = gxrow < N_NODES;
  const float* xbase = x + (size_t)gxrow * D_INF + lxp;
  const int lwr = tid >> 4;
  const int lwp = (tid & 15) << 2;
  const float* wbase = W1 + lwr * D_HID + lwp;

  float4 xv = xok ? *(const float4*)xbase : make_float4(0.f,0.f,0.f,0.f);
  float4 wv = *(const float4*)wbase;
  *(float4*)&xs[0][lxr][lxp] = xv;
  *(float4*)&ws[0][lwr][lwp] = wv;
  __syncthreads();

  float acc[4][4] = {};
  int b = 0;
  #pragma unroll 1
  for (int ks = 0; ks < D_INF / KB; ++ks){
    if (ks < D_INF / KB - 1){
      xv = xok ? *(const float4*)(xbase + (ks + 1) * KB) : make_float4(0.f,0.f,0.f,0.f);
      wv = *(const float4*)(wbase + (size_t)(ks + 1) * KB * D_HID);
    }
    #pragma unroll
    for (int k4 = 0; k4 < KB / 4; ++k4){
      float4 xr4[4];
      #pragma unroll
      for (int r = 0; r < 4; ++r)
        xr4[r] = *(float4*)&xs[b][(tr << 2) + r][k4 << 2];
      #pragma unroll
      for (int j = 0; j < 4; ++j){
        float4 w4 = *(float4*)&ws[b][(k4 << 2) + j][tc << 2];
        #pragma unroll
        for (int r = 0; r < 4; ++r){
          float xk = (j == 0) ? xr4[r].x : (j == 1) ? xr4[r].y : (j == 2) ? xr4[r].z : xr4[r].w;
          acc[r][0] = fmaf(xk, w4.x, acc[r][0]);
          acc[r][1] = fmaf(xk, w4.y, acc[r][1]);
          acc[r][2] = fmaf(xk, w4.z, acc[r][2]);
          acc[r][3] = fmaf(xk, w4.w, acc[r][3]);
        }
      }
    }
    if (ks < D_INF / KB - 1){
      *(float4*)&xs[b ^ 1][lxr][lxp] = xv;
      *(float4*)&ws[b ^ 1][lwr][lwp] = wv;
    }
    __syncthreads();
    b ^= 1;
  }

  float as0 = a_src[tc << 2], as1 = a_src[(tc << 2) + 1],
        as2 = a_src[(tc << 2) + 2], as3 = a_src[(tc << 2) + 3];
  float ad0 = a_dst[tc << 2], ad1 = a_dst[(tc << 2) + 1],
        ad2 = a_dst[(tc << 2) + 2], ad3 = a_dst[(tc << 2) + 3];
  #pragma unroll
  for (int r = 0; r < 4; ++r){
    int row = row0 + (tr << 2) + r;
    float ps = acc[r][0]*as0 + acc[r][1]*as1 + acc[r][2]*as2 + acc[r][3]*as3;
    float pd = acc[r][0]*ad0 + acc[r][1]*ad1 + acc[r][2]*ad2 + acc[r][3]*ad3;
    #pragma unroll
    for (int off = 1; off < 16; off <<= 1){
      ps += __shfl_xor(ps, off, 64);
      pd += __shfl_xor(pd, off, 64);
    }
    if (row < N_NODES){
      H4 u;
      u.h[0] = __floats2half2_rn(acc[r][0], acc[r][1]);
      u.h[1] = __floats2half2_rn(acc[r][2], acc[r][3]);
      *(float2*)&h1h[(size_t)row * D_HID + (tc << 2)] = u.f;
      if (tc == 0){ es[row] = ps; ed[row] = pd; }
    }
  }
}

// ------- layer 1 aggregation + bias + ELU + FUSED gemm2/3 + attention dots -------
__global__ __launch_bounds__(256) void k_agg1(const int* __restrict__ rowptr,
      const int* __restrict__ srcs,
      const __half* __restrict__ h1h, const float* __restrict__ es,
      const float* __restrict__ ed, const float* __restrict__ b1,
      const float* __restrict__ W2, const float* __restrict__ W3,
      const float* __restrict__ a2s, const float* __restrict__ a2d,
      const float* __restrict__ a3s, const float* __restrict__ a3d,
      __half* __restrict__ h23h, float2* __restrict__ es23,
      float2* __restrict__ edinv2, float* __restrict__ ed3){
  __shared__ float sW[D_HID * 64];          // [k][half*32+c], 16 KiB
  int t = threadIdx.x, lane = t & 63, wv = t >> 6;
  int half = lane >> 5, c = lane & 31;
  for (int idx = t; idx < D_HID * D_OUTF; idx += 256){
    int k = idx >> 5, cc = idx & 31;
    sW[k * 64 + cc]      = W2[idx];
    sW[k * 64 + 32 + cc] = W3[idx];
  }
  __syncthreads();

  int node = blockIdx.x * 4 + wv;
  int beg = rowptr[node], end = rowptr[node + 1];
  float edv = ed[node];
  float a0 = 0.f, a1 = 0.f, a2 = 0.f, a3 = 0.f, ss = 0.f;
  for (int i = beg; i < end; i += 8){
    int sA[8]; float v[8], p[8];
    #pragma unroll
    for (int u = 0; u < 8; ++u){
      int idx = i + u;
      sA[u] = srcs[(idx < end) ? idx : beg];
    }
    #pragma unroll
    for (int u = 0; u < 8; ++u)
      v[u] = __half2float(h1h[(size_t)sA[u] * D_HID + lane]);
    #pragma unroll
    for (int u = 0; u < 8; ++u){
      float e = __expf(leaky_relu(es[sA[u]] + edv));
      p[u] = (i + u < end) ? e : 0.f;
    }
    #pragma unroll
    for (int u = 0; u < 8; ++u){
      ss += p[u];
      float* a = (u & 3) == 0 ? &a0 : (u & 3) == 1 ? &a1 : (u & 3) == 2 ? &a2 : &a3;
      *a = fmaf(p[u], v[u], *a);
    }
  }
  float acc = (a0 + a1) + (a2 + a3);
  float o = acc / (ss + 1e-16f) + b1[lane];
  float hv = o > 0.f ? o : expm1f(o);       // h1act (node, lane), register-only

  // fused layer-2/3 linear: h23 row = h1act_row @ [W2 | W3]
  float a_s = half ? a3s[c] : a2s[c];
  float a_d = half ? a3d[c] : a2d[c];
  float g = 0.f;
  #pragma unroll
  for (int k = 0; k < D_HID; ++k){
    float xk = __shfl(hv, k, 64);
    g = fmaf(xk, sW[k * 64 + lane], g);
  }
  h23h[(size_t)node * 64 + lane] = __float2half_rn(g);
  float vs = g * a_s, vd = g * a_d;
  #pragma unroll
  for (int off = 16; off; off >>= 1){
    vs += __shfl_xor(vs, off, 64);
    vd += __shfl_xor(vd, off, 64);
  }
  if (c == 0){
    if (half){ es23[node].y = vs; ed3[node] = vd; }
    else     { es23[node].x = vs; edinv2[node].x = vd; }
  }
}

// ------- layers 2&3 aggregation + relu + linear + var; stores inv_s2 -------
__global__ __launch_bounds__(256) void k_agg23(const int* __restrict__ rowptr,
   const int* __restrict__ srcs,
   const __half* __restrict__ h23h,
   const float2* __restrict__ es23, float2* __restrict__ edinv2,
   const float* __restrict__ ed3,
   const float* __restrict__ b2, const float* __restrict__ b3,
   const float* __restrict__ Wlin, const float* __restrict__ blin,
   float* __restrict__ mean_out, float* __restrict__ var_out){
  __shared__ float sWl[D_OUTF * D_OUTF];
  int t = threadIdx.x, lane = t & 63, wv = t >> 6;
  int half = lane >> 5, c = lane & 31;
  for (int idx = t; idx < D_OUTF * D_OUTF; idx += 256) sWl[idx] = Wlin[idx];
  __syncthreads();

  int node = blockIdx.x * 4 + wv;
  int beg = rowptr[node], end = rowptr[node + 1];
  float edv = half ? ed3[node] : edinv2[node].x;
  float a0 = 0.f, a1 = 0.f, a2 = 0.f, a3 = 0.f, ss = 0.f;
  for (int i = beg; i < end; i += 8){
    int sA[8]; float v[8], p[8];
    #pragma unroll
    for (int u = 0; u < 8; ++u){
      int idx = i + u;
      sA[u] = srcs[(idx < end) ? idx : beg];
    }
    #pragma unroll
    for (int u = 0; u < 8; ++u)
      v[u] = __half2float(h23h[(size_t)sA[u] * 64 + lane]);
    #pragma unroll
    for (int u = 0; u < 8; ++u){
      float2 e2 = es23[sA[u]];
      float esv = half ? e2.y : e2.x;
      float e = __expf(leaky_relu(esv + edv));
      p[u] = (i + u < end) ? e : 0.f;
    }
    #pragma unroll
    for (int u = 0; u < 8; ++u){
      ss += p[u];
      float* a = (u & 3) == 0 ? &a0 : (u & 3) == 1 ? &a1 : (u & 3) == 2 ? &a2 : &a3;
      *a = fmaf(p[u], v[u], *a);
    }
  }
  if (half){  // layer-3 self loop
    float p = __expf(leaky_relu(es23[node].y + ed3[node]));
    ss += p;
    a0 = fmaf(p, __half2float(h23h[(size_t)node * 64 + lane]), a0);
  }
  float acc = (a0 + a1) + (a2 + a3);
  float stot = ss + 1e-16f;
  if (half){
    var_out[(size_t)node * D_OUTF + c] = acc / stot + b3[c];
  } else {
    float mean = acc / stot + b2[c];
    mean = mean > 0.f ? mean : 0.f;
    float o = blin[c];
    #pragma unroll
    for (int j = 0; j < D_OUTF; ++j){
      o = fmaf(__shfl(mean, j, 32), sWl[j * D_OUTF + c], o);
    }
    mean_out[(size_t)node * D_OUTF + c] = o;
    if (c == 0) edinv2[node].y = 1.f / stot;
  }
}

// ------- alpha: flat edge-parallel, coalesced write -------
__global__ __launch_bounds__(256) void k_alpha(const int* __restrict__ src,
    const int* __restrict__ dst,
    const float2* __restrict__ es23, const float2* __restrict__ edinv2,
    float* __restrict__ alpha_out){
  int e = blockIdx.x * blockDim.x + threadIdx.x;
  if (e < N_EDGES){
    int s = src[e], d = dst[e];
    float2 t = edinv2[d];
    alpha_out[e] = __expf(leaky_relu(es23[s].x + t.x)) * t.y;
  }
}

extern "C" void kernel_launch(void* const* d_in, const int* in_sizes, int n_in,
                              void* d_out, int out_size, void* d_ws, size_t ws_size,
                              hipStream_t stream) {
  const float* x   = (const float*)d_in[0];
  const int*   ei  = (const int*)d_in[1];
  const int*   src = ei;
  const int*   dst = ei + N_EDGES;
  const float* W1  = (const float*)d_in[2];
  const float* a1s = (const float*)d_in[3];
  const float* a1d = (const float*)d_in[4];
  const float* b1  = (const float*)d_in[5];
  const float* W2  = (const float*)d_in[6];
  const float* a2s = (const float*)d_in[7];
  const float* a2d = (const float*)d_in[8];
  const float* b2  = (const float*)d_in[9];
  const float* W3  = (const float*)d_in[10];
  const float* a3s = (const float*)d_in[11];
  const float* a3d = (const float*)d_in[12];
  const float* b3  = (const float*)d_in[13];
  const float* Wl  = (const float*)d_in[14];
  const float* bl  = (const float*)d_in[15];

  float* out       = (float*)d_out;
  float* mean_out  = out;
  float* var_out   = out + (size_t)N_NODES * D_OUTF;
  float* alpha_out = out + 2 * (size_t)N_NODES * D_OUTF;

  int* deg      = (int*)d_ws;                 // N
  int* wcount   = deg + N_NODES;              // N
  int* rowptr   = wcount + N_NODES;           // N+1
  int* srcs     = rowptr + (N_NODES + 1);     // E
  __half* h1h   = (__half*)(srcs + N_EDGES + 1);   // +1 int pad -> 8B aligned
  __half* h23h  = h1h + (size_t)N_NODES * 64;
  float* es1    = (float*)(h23h + (size_t)N_NODES * 64);
  float* ed1    = es1 + N_NODES;
  float* ed3    = ed1 + N_NODES;
  float2* es23  = (float2*)(ed3 + N_NODES);
  float2* edinv2= es23 + N_NODES;

  hipMemsetAsync(deg, 0, 2 * (size_t)N_NODES * sizeof(int), stream);

  k_deg <<<(N_EDGES + 255) / 256, 256, 0, stream>>>(dst, deg);
  k_scan<<<1, 1024, 0, stream>>>(deg, rowptr);
  k_fill<<<(N_EDGES + 255) / 256, 256, 0, stream>>>(src, dst, rowptr, wcount, srcs);

  k_gemm1<<<(N_NODES + MT - 1) / MT, 256, 0, stream>>>(x, W1, a1s, a1d, h1h, es1, ed1);
  k_agg1 <<<N_NODES / 4, 256, 0, stream>>>(rowptr, srcs, h1h, es1, ed1, b1,
                                           W2, W3, a2s, a2d, a3s, a3d,
                                           h23h, es23, edinv2, ed3);
  k_agg23<<<N_NODES / 4, 256, 0, stream>>>(rowptr, srcs, h23h,
                                           es23, edinv2, ed3, b2, b3, Wl, bl,
                                           mean_out, var_out);
  k_alpha<<<(N_EDGES + 255) / 256, 256, 0, stream>>>(src, dst, es23, edinv2, alpha_out);
}

// Round 5
// 264.863 us; speedup vs baseline: 1.8628x; 1.1507x over previous
//
#include <hip/hip_runtime.h>
#include <hip/hip_fp16.h>
#include <math.h>

#define N_NODES 50000
#define N_EDGES 800000
#define D_INF   256
#define D_HID   64
#define D_OUTF  32
#define LEAKY   0.2f

#define MT 64     // gemm1 M-tile rows
#define KB 16     // gemm1 K-step

__device__ __forceinline__ float leaky_relu(float x){ return x >= 0.f ? x : LEAKY * x; }

union H4 { __half2 h[2]; float2 f; };

// ---------------- CSR build ----------------
__global__ void k_deg(const int* __restrict__ dst, int* __restrict__ deg){
  int i = blockIdx.x * blockDim.x + threadIdx.x;
  if (i < N_EDGES) atomicAdd(&deg[dst[i]], 1);
}

// parallel scan: A) block sums  B) scan of block sums  C) scatter scanned rowptr
__global__ __launch_bounds__(256) void k_scan_a(const int* __restrict__ deg, int* __restrict__ bsum){
  __shared__ int ws[4];
  int b = blockIdx.x, t = threadIdx.x, i = b * 256 + t;
  int x = (i < N_NODES) ? deg[i] : 0;
  #pragma unroll
  for (int off = 32; off; off >>= 1) x += __shfl_down(x, off, 64);
  if ((t & 63) == 0) ws[t >> 6] = x;
  __syncthreads();
  if (t == 0) bsum[b] = ws[0] + ws[1] + ws[2] + ws[3];
}

__global__ __launch_bounds__(256) void k_scan_b(int* __restrict__ bsum, int nb){
  __shared__ int ws[4];
  int t = threadIdx.x, lane = t & 63, wv = t >> 6;
  int x = (t < nb) ? bsum[t] : 0;
  #pragma unroll
  for (int off = 1; off < 64; off <<= 1){
    int y = __shfl_up(x, off, 64);
    if (lane >= off) x += y;
  }
  if (lane == 63) ws[wv] = x;
  __syncthreads();
  int add = 0;
  for (int w = 0; w < wv; ++w) add += ws[w];
  x += add;
  if (t < nb) bsum[t] = x;   // inclusive
}

__global__ __launch_bounds__(256) void k_scan_c(const int* __restrict__ deg,
        const int* __restrict__ bsum, int* __restrict__ rowptr){
  __shared__ int ws[4];
  int b = blockIdx.x, t = threadIdx.x, i = b * 256 + t;
  int lane = t & 63, wv = t >> 6;
  int x = (i < N_NODES) ? deg[i] : 0;
  #pragma unroll
  for (int off = 1; off < 64; off <<= 1){
    int y = __shfl_up(x, off, 64);
    if (lane >= off) x += y;
  }
  if (lane == 63) ws[wv] = x;
  __syncthreads();
  int add = (b > 0) ? bsum[b - 1] : 0;
  for (int w = 0; w < wv; ++w) add += ws[w];
  x += add;
  if (i < N_NODES) rowptr[i + 1] = x;
  if (b == 0 && t == 0) rowptr[0] = 0;
}

__global__ void k_fill(const int* __restrict__ src, const int* __restrict__ dst,
                       const int* __restrict__ rowptr, int* __restrict__ wcount,
                       int* __restrict__ srcs){
  int i = blockIdx.x * blockDim.x + threadIdx.x;
  if (i < N_EDGES){
    int d = dst[i];
    int pos = rowptr[d] + atomicAdd(&wcount[d], 1);
    srcs[pos] = src[i];
  }
}

// ---------------- layer 1 GEMM: h1 = x@W1 (tiled, fp16 out), es1/ed1 dots ----------------
__global__ __launch_bounds__(256) void k_gemm1(const float* __restrict__ x,
        const float* __restrict__ W1,
        const float* __restrict__ a_src, const float* __restrict__ a_dst,
        __half* __restrict__ h1h, float* __restrict__ es, float* __restrict__ ed){
  __shared__ float xs[2][MT][KB + 4];
  __shared__ float ws[2][KB][D_HID];
  const int tid = threadIdx.x;
  const int tc  = tid & 15;
  const int tr  = tid >> 4;
  const int row0 = blockIdx.x * MT;

  const int lxr = tid >> 2;
  const int lxp = (tid & 3) << 2;
  const int gxrow = row0 + lxr;
  const bool xok = gxrow < N_NODES;
  const float* xbase = x + (size_t)gxrow * D_INF + lxp;
  const int lwr = tid >> 4;
  const int lwp = (tid & 15) << 2;
  const float* wbase = W1 + lwr * D_HID + lwp;

  float4 xv = xok ? *(const float4*)xbase : make_float4(0.f,0.f,0.f,0.f);
  float4 wv = *(const float4*)wbase;
  *(float4*)&xs[0][lxr][lxp] = xv;
  *(float4*)&ws[0][lwr][lwp] = wv;
  __syncthreads();

  float acc[4][4] = {};
  int b = 0;
  #pragma unroll 1
  for (int ks = 0; ks < D_INF / KB; ++ks){
    if (ks < D_INF / KB - 1){
      xv = xok ? *(const float4*)(xbase + (ks + 1) * KB) : make_float4(0.f,0.f,0.f,0.f);
      wv = *(const float4*)(wbase + (size_t)(ks + 1) * KB * D_HID);
    }
    #pragma unroll
    for (int k4 = 0; k4 < KB / 4; ++k4){
      float4 xr4[4];
      #pragma unroll
      for (int r = 0; r < 4; ++r)
        xr4[r] = *(float4*)&xs[b][(tr << 2) + r][k4 << 2];
      #pragma unroll
      for (int j = 0; j < 4; ++j){
        float4 w4 = *(float4*)&ws[b][(k4 << 2) + j][tc << 2];
        #pragma unroll
        for (int r = 0; r < 4; ++r){
          float xk = (j == 0) ? xr4[r].x : (j == 1) ? xr4[r].y : (j == 2) ? xr4[r].z : xr4[r].w;
          acc[r][0] = fmaf(xk, w4.x, acc[r][0]);
          acc[r][1] = fmaf(xk, w4.y, acc[r][1]);
          acc[r][2] = fmaf(xk, w4.z, acc[r][2]);
          acc[r][3] = fmaf(xk, w4.w, acc[r][3]);
        }
      }
    }
    if (ks < D_INF / KB - 1){
      *(float4*)&xs[b ^ 1][lxr][lxp] = xv;
      *(float4*)&ws[b ^ 1][lwr][lwp] = wv;
    }
    __syncthreads();
    b ^= 1;
  }

  float as0 = a_src[tc << 2], as1 = a_src[(tc << 2) + 1],
        as2 = a_src[(tc << 2) + 2], as3 = a_src[(tc << 2) + 3];
  float ad0 = a_dst[tc << 2], ad1 = a_dst[(tc << 2) + 1],
        ad2 = a_dst[(tc << 2) + 2], ad3 = a_dst[(tc << 2) + 3];
  #pragma unroll
  for (int r = 0; r < 4; ++r){
    int row = row0 + (tr << 2) + r;
    float ps = acc[r][0]*as0 + acc[r][1]*as1 + acc[r][2]*as2 + acc[r][3]*as3;
    float pd = acc[r][0]*ad0 + acc[r][1]*ad1 + acc[r][2]*ad2 + acc[r][3]*ad3;
    #pragma unroll
    for (int off = 1; off < 16; off <<= 1){
      ps += __shfl_xor(ps, off, 64);
      pd += __shfl_xor(pd, off, 64);
    }
    if (row < N_NODES){
      H4 u;
      u.h[0] = __floats2half2_rn(acc[r][0], acc[r][1]);
      u.h[1] = __floats2half2_rn(acc[r][2], acc[r][3]);
      *(float2*)&h1h[(size_t)row * D_HID + (tc << 2)] = u.f;
      if (tc == 0){ es[row] = ps; ed[row] = pd; }
    }
  }
}

// ------- layer 1 aggregation (dual-edge half2) + bias + ELU + FUSED gemm2/3 -------
__global__ __launch_bounds__(256) void k_agg1(const int* __restrict__ rowptr,
      const int* __restrict__ srcs,
      const __half* __restrict__ h1h, const float* __restrict__ es,
      const float* __restrict__ ed, const float* __restrict__ b1,
      const float* __restrict__ W2, const float* __restrict__ W3,
      const float* __restrict__ a2s, const float* __restrict__ a2d,
      const float* __restrict__ a3s, const float* __restrict__ a3d,
      __half* __restrict__ h23h, float2* __restrict__ es23,
      float2* __restrict__ edinv2, float* __restrict__ ed3){
  __shared__ float sW[D_HID * 64];          // [k][col], col<32 -> W2, col>=32 -> W3
  int t = threadIdx.x, lane = t & 63, wv = t >> 6;
  int eslot = lane >> 5, c2 = lane & 31;
  for (int idx = t; idx < D_HID * D_OUTF; idx += 256){
    int k = idx >> 5, cc = idx & 31;
    sW[k * 64 + cc]      = W2[idx];
    sW[k * 64 + 32 + cc] = W3[idx];
  }
  __syncthreads();

  int node = blockIdx.x * 4 + wv;
  int beg = rowptr[node], end = rowptr[node + 1];
  float edv = ed[node];
  float2 a0 = {0,0}, a1 = {0,0}, a2 = {0,0}, a3 = {0,0};
  float ss = 0.f;
  #pragma unroll 1
  for (int base = beg; base < end; base += 16){
    int sA[8]; float2 v[8]; float p[8];
    int eb = base + (eslot << 3);
    #pragma unroll
    for (int u = 0; u < 8; ++u){
      int idx = eb + u;
      sA[u] = srcs[(idx < end) ? idx : beg];
    }
    #pragma unroll
    for (int u = 0; u < 8; ++u)
      v[u] = __half22float2(*(const __half2*)&h1h[(size_t)sA[u] * D_HID + (c2 << 1)]);
    #pragma unroll
    for (int u = 0; u < 8; ++u){
      float e = __expf(leaky_relu(es[sA[u]] + edv));
      p[u] = (eb + u < end) ? e : 0.f;
    }
    #pragma unroll
    for (int u = 0; u < 8; ++u){
      ss += p[u];
      float2* a = (u & 3) == 0 ? &a0 : (u & 3) == 1 ? &a1 : (u & 3) == 2 ? &a2 : &a3;
      a->x = fmaf(p[u], v[u].x, a->x);
      a->y = fmaf(p[u], v[u].y, a->y);
    }
  }
  float2 acc2;
  acc2.x = (a0.x + a1.x) + (a2.x + a3.x);
  acc2.y = (a0.y + a1.y) + (a2.y + a3.y);
  // merge the two 8-edge halves
  acc2.x += __shfl_xor(acc2.x, 32, 64);
  acc2.y += __shfl_xor(acc2.y, 32, 64);
  ss    += __shfl_xor(ss, 32, 64);

  float inv = 1.f / (ss + 1e-16f);
  float2 b1v = *(const float2*)&b1[c2 << 1];
  float ox = acc2.x * inv + b1v.x;
  float oy = acc2.y * inv + b1v.y;
  float2 hv;
  hv.x = ox > 0.f ? ox : expm1f(ox);
  hv.y = oy > 0.f ? oy : expm1f(oy);      // h1act channels 2c2, 2c2+1

  // fused layer-2/3 linear: col = lane
  int hf = lane >> 5, c = lane & 31;
  float a_s = hf ? a3s[c] : a2s[c];
  float a_d = hf ? a3d[c] : a2d[c];
  float g = 0.f;
  #pragma unroll
  for (int k2 = 0; k2 < 32; ++k2){
    float hx = __shfl(hv.x, k2, 64);
    float hy = __shfl(hv.y, k2, 64);
    g = fmaf(hx, sW[(k2 * 2) * 64 + lane], g);
    g = fmaf(hy, sW[(k2 * 2 + 1) * 64 + lane], g);
  }
  h23h[(size_t)node * 64 + lane] = __float2half_rn(g);
  float vs = g * a_s, vd = g * a_d;
  #pragma unroll
  for (int off = 16; off; off >>= 1){
    vs += __shfl_xor(vs, off, 64);
    vd += __shfl_xor(vd, off, 64);
  }
  if (c == 0){
    if (hf){ es23[node].y = vs; ed3[node] = vd; }
    else   { es23[node].x = vs; edinv2[node].x = vd; }
  }
}

// ------- layers 2&3 aggregation (dual-edge half2) + relu + linear + var -------
__global__ __launch_bounds__(256) void k_agg23(const int* __restrict__ rowptr,
   const int* __restrict__ srcs,
   const __half* __restrict__ h23h,
   const float2* __restrict__ es23, float2* __restrict__ edinv2,
   const float* __restrict__ ed3,
   const float* __restrict__ b2, const float* __restrict__ b3,
   const float* __restrict__ Wlin, const float* __restrict__ blin,
   float* __restrict__ mean_out, float* __restrict__ var_out){
  __shared__ float sWl[D_OUTF * D_OUTF];
  int t = threadIdx.x, lane = t & 63, wv = t >> 6;
  int eslot = lane >> 5, c2 = lane & 31;
  int layer = c2 >> 4;                   // 0: layer-2 (mean), 1: layer-3 (var)
  int cc = (c2 & 15) << 1;               // channel pair within the 32-wide output
  for (int idx = t; idx < D_OUTF * D_OUTF; idx += 256) sWl[idx] = Wlin[idx];
  __syncthreads();

  int node = blockIdx.x * 4 + wv;
  int beg = rowptr[node], end = rowptr[node + 1];
  float edv = layer ? ed3[node] : edinv2[node].x;
  float2 a0 = {0,0}, a1 = {0,0}, a2 = {0,0}, a3 = {0,0};
  float ss = 0.f;
  #pragma unroll 1
  for (int base = beg; base < end; base += 16){
    int sA[8]; float2 v[8]; float p[8];
    int eb = base + (eslot << 3);
    #pragma unroll
    for (int u = 0; u < 8; ++u){
      int idx = eb + u;
      sA[u] = srcs[(idx < end) ? idx : beg];
    }
    #pragma unroll
    for (int u = 0; u < 8; ++u)
      v[u] = __half22float2(*(const __half2*)&h23h[(size_t)sA[u] * 64 + (c2 << 1)]);
    #pragma unroll
    for (int u = 0; u < 8; ++u){
      float2 e2 = es23[sA[u]];
      float esv = layer ? e2.y : e2.x;
      float e = __expf(leaky_relu(esv + edv));
      p[u] = (eb + u < end) ? e : 0.f;
    }
    #pragma unroll
    for (int u = 0; u < 8; ++u){
      ss += p[u];
      float2* a = (u & 3) == 0 ? &a0 : (u & 3) == 1 ? &a1 : (u & 3) == 2 ? &a2 : &a3;
      a->x = fmaf(p[u], v[u].x, a->x);
      a->y = fmaf(p[u], v[u].y, a->y);
    }
  }
  float2 acc2;
  acc2.x = (a0.x + a1.x) + (a2.x + a3.x);
  acc2.y = (a0.y + a1.y) + (a2.y + a3.y);
  acc2.x += __shfl_xor(acc2.x, 32, 64);
  acc2.y += __shfl_xor(acc2.y, 32, 64);
  ss    += __shfl_xor(ss, 32, 64);

  if (layer){  // layer-3 self loop
    float ps = __expf(leaky_relu(es23[node].y + ed3[node]));
    ss += ps;
    float2 hv = __half22float2(*(const __half2*)&h23h[(size_t)node * 64 + (c2 << 1)]);
    acc2.x = fmaf(ps, hv.x, acc2.x);
    acc2.y = fmaf(ps, hv.y, acc2.y);
  }
  float inv = 1.f / (ss + 1e-16f);
  if (layer){
    if (eslot == 0){
      float2 o = { acc2.x * inv + b3[cc], acc2.y * inv + b3[cc + 1] };
      *(float2*)&var_out[(size_t)node * D_OUTF + cc] = o;
    }
  } else {
    float2 mean;
    mean.x = acc2.x * inv + b2[cc];
    mean.y = acc2.y * inv + b2[cc + 1];
    mean.x = mean.x > 0.f ? mean.x : 0.f;
    mean.y = mean.y > 0.f ? mean.y : 0.f;
    float2 o = *(const float2*)&blin[cc];
    #pragma unroll
    for (int j2 = 0; j2 < 16; ++j2){
      float mjx = __shfl(mean.x, j2, 64);
      float mjy = __shfl(mean.y, j2, 64);
      float2 w0 = *(float2*)&sWl[(j2 * 2) * D_OUTF + cc];
      float2 w1 = *(float2*)&sWl[(j2 * 2 + 1) * D_OUTF + cc];
      o.x = fmaf(mjx, w0.x, o.x); o.x = fmaf(mjy, w1.x, o.x);
      o.y = fmaf(mjx, w0.y, o.y); o.y = fmaf(mjy, w1.y, o.y);
    }
    if (eslot == 0)
      *(float2*)&mean_out[(size_t)node * D_OUTF + cc] = o;
    if (lane == 0) edinv2[node].y = inv;
  }
}

// ------- alpha: flat edge-parallel, coalesced write -------
__global__ __launch_bounds__(256) void k_alpha(const int* __restrict__ src,
    const int* __restrict__ dst,
    const float2* __restrict__ es23, const float2* __restrict__ edinv2,
    float* __restrict__ alpha_out){
  int e = blockIdx.x * blockDim.x + threadIdx.x;
  if (e < N_EDGES){
    int s = src[e], d = dst[e];
    float2 t = edinv2[d];
    alpha_out[e] = __expf(leaky_relu(es23[s].x + t.x)) * t.y;
  }
}

extern "C" void kernel_launch(void* const* d_in, const int* in_sizes, int n_in,
                              void* d_out, int out_size, void* d_ws, size_t ws_size,
                              hipStream_t stream) {
  const float* x   = (const float*)d_in[0];
  const int*   ei  = (const int*)d_in[1];
  const int*   src = ei;
  const int*   dst = ei + N_EDGES;
  const float* W1  = (const float*)d_in[2];
  const float* a1s = (const float*)d_in[3];
  const float* a1d = (const float*)d_in[4];
  const float* b1  = (const float*)d_in[5];
  const float* W2  = (const float*)d_in[6];
  const float* a2s = (const float*)d_in[7];
  const float* a2d = (const float*)d_in[8];
  const float* b2  = (const float*)d_in[9];
  const float* W3  = (const float*)d_in[10];
  const float* a3s = (const float*)d_in[11];
  const float* a3d = (const float*)d_in[12];
  const float* b3  = (const float*)d_in[13];
  const float* Wl  = (const float*)d_in[14];
  const float* bl  = (const float*)d_in[15];

  float* out       = (float*)d_out;
  float* mean_out  = out;
  float* var_out   = out + (size_t)N_NODES * D_OUTF;
  float* alpha_out = out + 2 * (size_t)N_NODES * D_OUTF;

  const int NSCAN = (N_NODES + 255) / 256;       // 196

  int* deg      = (int*)d_ws;                 // N
  int* wcount   = deg + N_NODES;              // N
  int* rowptr   = wcount + N_NODES;           // N+1
  int* bsum     = rowptr + (N_NODES + 1);     // NSCAN (+pad to keep 8B align below)
  int* srcs     = bsum + NSCAN;               // E
  __half* h1h   = (__half*)(srcs + N_EDGES + 1);   // pad -> 8B aligned
  __half* h23h  = h1h + (size_t)N_NODES * 64;
  float* es1    = (float*)(h23h + (size_t)N_NODES * 64);
  float* ed1    = es1 + N_NODES;
  float* ed3    = ed1 + N_NODES;
  float2* es23  = (float2*)(ed3 + N_NODES);
  float2* edinv2= es23 + N_NODES;

  hipMemsetAsync(deg, 0, 2 * (size_t)N_NODES * sizeof(int), stream);

  k_deg   <<<(N_EDGES + 255) / 256, 256, 0, stream>>>(dst, deg);
  k_scan_a<<<NSCAN, 256, 0, stream>>>(deg, bsum);
  k_scan_b<<<1, 256, 0, stream>>>(bsum, NSCAN);
  k_scan_c<<<NSCAN, 256, 0, stream>>>(deg, bsum, rowptr);
  k_fill  <<<(N_EDGES + 255) / 256, 256, 0, stream>>>(src, dst, rowptr, wcount, srcs);

  k_gemm1<<<(N_NODES + MT - 1) / MT, 256, 0, stream>>>(x, W1, a1s, a1d, h1h, es1, ed1);
  k_agg1 <<<N_NODES / 4, 256, 0, stream>>>(rowptr, srcs, h1h, es1, ed1, b1,
                                           W2, W3, a2s, a2d, a3s, a3d,
                                           h23h, es23, edinv2, ed3);
  k_agg23<<<N_NODES / 4, 256, 0, stream>>>(rowptr, srcs, h23h,
                                           es23, edinv2, ed3, b2, b3, Wl, bl,
                                           mean_out, var_out);
  k_alpha<<<(N_EDGES + 255) / 256, 256, 0, stream>>>(src, dst, es23, edinv2, alpha_out);
}

// Round 6
// 248.691 us; speedup vs baseline: 1.9840x; 1.0650x over previous
//
#include <hip/hip_runtime.h>
#include <hip/hip_fp16.h>
#include <math.h>

#define N_NODES 50000
#define N_EDGES 800000
#define D_INF   256
#define D_HID   64
#define D_OUTF  32
#define LEAKY   0.2f

#define MT 64     // gemm1 M-tile rows
#define KB 16     // gemm1 K-step

__device__ __forceinline__ float leaky_relu(float x){ return x >= 0.f ? x : LEAKY * x; }

union H4 { __half2 h[2]; float2 f; };
union H8 { __half2 h[4]; float4 f; };

// u32 byte-offset gather helpers (enables s[base]+v[u32] addressing)
__device__ __forceinline__ __half2 ldg_h2(const __half* base, unsigned byteoff){
  return *(const __half2*)((const char*)base + byteoff);
}
__device__ __forceinline__ float ldg_f(const float* base, unsigned byteoff){
  return *(const float*)((const char*)base + byteoff);
}
__device__ __forceinline__ float2 ldg_f2(const float2* base, unsigned byteoff){
  return *(const float2*)((const char*)base + byteoff);
}

// ---------------- CSR build ----------------
__global__ void k_deg(const int* __restrict__ dst, int* __restrict__ deg){
  int i = blockIdx.x * blockDim.x + threadIdx.x;
  if (i < N_EDGES) atomicAdd(&deg[dst[i]], 1);
}

// parallel scan: A) block sums  B) scan of block sums (+ prew dot-vectors)  C) scatter
__global__ __launch_bounds__(256) void k_scan_a(const int* __restrict__ deg, int* __restrict__ bsum){
  __shared__ int ws[4];
  int b = blockIdx.x, t = threadIdx.x, i = b * 256 + t;
  int x = (i < N_NODES) ? deg[i] : 0;
  #pragma unroll
  for (int off = 32; off; off >>= 1) x += __shfl_down(x, off, 64);
  if ((t & 63) == 0) ws[t >> 6] = x;
  __syncthreads();
  if (t == 0) bsum[b] = ws[0] + ws[1] + ws[2] + ws[3];
}

__global__ __launch_bounds__(256) void k_scan_b(int* __restrict__ bsum, int nb,
      const float* __restrict__ W2, const float* __restrict__ W3,
      const float* __restrict__ a2s, const float* __restrict__ a2d,
      const float* __restrict__ a3s, const float* __restrict__ a3d,
      float* __restrict__ prew){
  __shared__ int ws[4];
  int t = threadIdx.x, lane = t & 63, wv = t >> 6;
  int x = (t < nb) ? bsum[t] : 0;
  #pragma unroll
  for (int off = 1; off < 64; off <<= 1){
    int y = __shfl_up(x, off, 64);
    if (lane >= off) x += y;
  }
  if (lane == 63) ws[wv] = x;
  __syncthreads();
  int add = 0;
  for (int w = 0; w < wv; ++w) add += ws[w];
  x += add;
  if (t < nb) bsum[t] = x;   // inclusive

  // prew: [w2s | w2d | w3s | w3d], each 64 floats. prew[vec*64+k] = sum_c W[k][c]*a[c]
  int vec = t >> 6, k = t & 63;
  const float* W = (vec < 2) ? W2 : W3;
  const float* a = (vec == 0) ? a2s : (vec == 1) ? a2d : (vec == 2) ? a3s : a3d;
  float s = 0.f;
  #pragma unroll 8
  for (int c = 0; c < D_OUTF; ++c) s = fmaf(W[k * D_OUTF + c], a[c], s);
  prew[t] = s;
}

__global__ __launch_bounds__(256) void k_scan_c(const int* __restrict__ deg,
        const int* __restrict__ bsum, int* __restrict__ rowptr){
  __shared__ int ws[4];
  int b = blockIdx.x, t = threadIdx.x, i = b * 256 + t;
  int lane = t & 63, wv = t >> 6;
  int x = (i < N_NODES) ? deg[i] : 0;
  #pragma unroll
  for (int off = 1; off < 64; off <<= 1){
    int y = __shfl_up(x, off, 64);
    if (lane >= off) x += y;
  }
  if (lane == 63) ws[wv] = x;
  __syncthreads();
  int add = (b > 0) ? bsum[b - 1] : 0;
  for (int w = 0; w < wv; ++w) add += ws[w];
  x += add;
  if (i < N_NODES) rowptr[i + 1] = x;
  if (b == 0 && t == 0) rowptr[0] = 0;
}

__global__ void k_fill(const int* __restrict__ src, const int* __restrict__ dst,
                       const int* __restrict__ rowptr, int* __restrict__ wcount,
                       int* __restrict__ srcs){
  int i = blockIdx.x * blockDim.x + threadIdx.x;
  if (i < N_EDGES){
    int d = dst[i];
    int pos = rowptr[d] + atomicAdd(&wcount[d], 1);
    srcs[pos] = src[i];
  }
}

// ---------------- layer 1 GEMM: h1 = x@W1 (tiled, fp16 out), es1/ed1 dots ----------------
__global__ __launch_bounds__(256) void k_gemm1(const float* __restrict__ x,
        const float* __restrict__ W1,
        const float* __restrict__ a_src, const float* __restrict__ a_dst,
        __half* __restrict__ h1h, float* __restrict__ es, float* __restrict__ ed){
  __shared__ float xs[2][MT][KB + 4];
  __shared__ float ws[2][KB][D_HID];
  const int tid = threadIdx.x;
  const int tc  = tid & 15;
  const int tr  = tid >> 4;
  const int row0 = blockIdx.x * MT;

  const int lxr = tid >> 2;
  const int lxp = (tid & 3) << 2;
  const int gxrow = row0 + lxr;
  const bool xok = gxrow < N_NODES;
  const float* xbase = x + (size_t)gxrow * D_INF + lxp;
  const int lwr = tid >> 4;
  const int lwp = (tid & 15) << 2;
  const float* wbase = W1 + lwr * D_HID + lwp;

  float4 xv = xok ? *(const float4*)xbase : make_float4(0.f,0.f,0.f,0.f);
  float4 wv = *(const float4*)wbase;
  *(float4*)&xs[0][lxr][lxp] = xv;
  *(float4*)&ws[0][lwr][lwp] = wv;
  __syncthreads();

  float acc[4][4] = {};
  int b = 0;
  #pragma unroll 1
  for (int ks = 0; ks < D_INF / KB; ++ks){
    if (ks < D_INF / KB - 1){
      xv = xok ? *(const float4*)(xbase + (ks + 1) * KB) : make_float4(0.f,0.f,0.f,0.f);
      wv = *(const float4*)(wbase + (size_t)(ks + 1) * KB * D_HID);
    }
    #pragma unroll
    for (int k4 = 0; k4 < KB / 4; ++k4){
      float4 xr4[4];
      #pragma unroll
      for (int r = 0; r < 4; ++r)
        xr4[r] = *(float4*)&xs[b][(tr << 2) + r][k4 << 2];
      #pragma unroll
      for (int j = 0; j < 4; ++j){
        float4 w4 = *(float4*)&ws[b][(k4 << 2) + j][tc << 2];
        #pragma unroll
        for (int r = 0; r < 4; ++r){
          float xk = (j == 0) ? xr4[r].x : (j == 1) ? xr4[r].y : (j == 2) ? xr4[r].z : xr4[r].w;
          acc[r][0] = fmaf(xk, w4.x, acc[r][0]);
          acc[r][1] = fmaf(xk, w4.y, acc[r][1]);
          acc[r][2] = fmaf(xk, w4.z, acc[r][2]);
          acc[r][3] = fmaf(xk, w4.w, acc[r][3]);
        }
      }
    }
    if (ks < D_INF / KB - 1){
      *(float4*)&xs[b ^ 1][lxr][lxp] = xv;
      *(float4*)&ws[b ^ 1][lwr][lwp] = wv;
    }
    __syncthreads();
    b ^= 1;
  }

  float as0 = a_src[tc << 2], as1 = a_src[(tc << 2) + 1],
        as2 = a_src[(tc << 2) + 2], as3 = a_src[(tc << 2) + 3];
  float ad0 = a_dst[tc << 2], ad1 = a_dst[(tc << 2) + 1],
        ad2 = a_dst[(tc << 2) + 2], ad3 = a_dst[(tc << 2) + 3];
  #pragma unroll
  for (int r = 0; r < 4; ++r){
    int row = row0 + (tr << 2) + r;
    float ps = acc[r][0]*as0 + acc[r][1]*as1 + acc[r][2]*as2 + acc[r][3]*as3;
    float pd = acc[r][0]*ad0 + acc[r][1]*ad1 + acc[r][2]*ad2 + acc[r][3]*ad3;
    #pragma unroll
    for (int off = 1; off < 16; off <<= 1){
      ps += __shfl_xor(ps, off, 64);
      pd += __shfl_xor(pd, off, 64);
    }
    if (row < N_NODES){
      H4 u;
      u.h[0] = __floats2half2_rn(acc[r][0], acc[r][1]);
      u.h[1] = __floats2half2_rn(acc[r][2], acc[r][3]);
      *(float2*)&h1h[(size_t)row * D_HID + (tc << 2)] = u.f;
      if (tc == 0){ es[row] = ps; ed[row] = pd; }
    }
  }
}

// ------- layer 1 aggregation (pure gather) + bias + ELU + attention-dot scalars -------
__global__ __launch_bounds__(256) void k_agg1(const int* __restrict__ rowptr,
      const int* __restrict__ srcs,
      const __half* __restrict__ h1h, const float* __restrict__ es,
      const float* __restrict__ ed, const float* __restrict__ b1,
      const float* __restrict__ prew,
      __half* __restrict__ h1acth, float2* __restrict__ es23,
      float2* __restrict__ edinv2, float* __restrict__ ed3){
  int t = threadIdx.x, lane = t & 63, wv = t >> 6;
  int eslot = lane >> 5, c2 = lane & 31;

  int node = blockIdx.x * 4 + wv;
  int beg = rowptr[node], end = rowptr[node + 1];
  float edv = ed[node];
  float2 a0 = {0,0}, a1 = {0,0}, a2 = {0,0}, a3 = {0,0};
  float ss = 0.f;
  #pragma unroll 1
  for (int base = beg; base < end; base += 16){
    int sA[8]; float2 v[8]; float p[8];
    int eb = base + (eslot << 3);
    #pragma unroll
    for (int u = 0; u < 8; ++u){
      int idx = eb + u;
      sA[u] = srcs[(idx < end) ? idx : beg];
    }
    #pragma unroll
    for (int u = 0; u < 8; ++u)
      v[u] = __half22float2(ldg_h2(h1h, (unsigned)(sA[u] * 128 + (c2 << 2))));
    #pragma unroll
    for (int u = 0; u < 8; ++u){
      float e = __expf(leaky_relu(ldg_f(es, (unsigned)(sA[u] << 2)) + edv));
      p[u] = (eb + u < end) ? e : 0.f;
    }
    #pragma unroll
    for (int u = 0; u < 8; ++u){
      ss += p[u];
      float2* a = (u & 3) == 0 ? &a0 : (u & 3) == 1 ? &a1 : (u & 3) == 2 ? &a2 : &a3;
      a->x = fmaf(p[u], v[u].x, a->x);
      a->y = fmaf(p[u], v[u].y, a->y);
    }
  }
  float2 acc2;
  acc2.x = (a0.x + a1.x) + (a2.x + a3.x);
  acc2.y = (a0.y + a1.y) + (a2.y + a3.y);
  // merge the two 8-edge halves
  acc2.x += __shfl_xor(acc2.x, 32, 64);
  acc2.y += __shfl_xor(acc2.y, 32, 64);
  ss    += __shfl_xor(ss, 32, 64);

  float inv = 1.f / (ss + 1e-16f);
  float2 b1v = *(const float2*)&b1[c2 << 1];
  float ox = acc2.x * inv + b1v.x;
  float oy = acc2.y * inv + b1v.y;
  float2 hv;
  hv.x = ox > 0.f ? ox : expm1f(ox);
  hv.y = oy > 0.f ? oy : expm1f(oy);      // h1act channels 2c2, 2c2+1 (both halves identical)

  if (eslot == 0){
    H4 u; u.h[0] = __floats2half2_rn(hv.x, hv.y);
    *(__half2*)&h1acth[(size_t)node * D_HID + (c2 << 1)] = u.h[0];
  }

  // attention-dot scalars: half0 -> layer2 (es2, ed2), half1 -> layer3 (es3, ed3)
  const float* pb = prew + (eslot ? 128 : 0);
  float2 wsv = *(const float2*)&pb[c2 << 1];
  float2 wdv = *(const float2*)&pb[64 + (c2 << 1)];
  float psum = hv.x * wsv.x + hv.y * wsv.y;
  float pdum = hv.x * wdv.x + hv.y * wdv.y;
  #pragma unroll
  for (int off = 1; off < 32; off <<= 1){
    psum += __shfl_xor(psum, off, 64);
    pdum += __shfl_xor(pdum, off, 64);
  }
  if (c2 == 0){
    if (eslot){ es23[node].y = psum; ed3[node] = pdum; }
    else      { es23[node].x = psum; edinv2[node].x = pdum; }
  }
}

// ---------------- dense GEMM: h23 = h1act(fp16) @ [W2 | W3] -> fp16 ----------------
__global__ __launch_bounds__(256) void k_gemm23(const __half* __restrict__ h1acth,
        const float* __restrict__ W2, const float* __restrict__ W3,
        __half* __restrict__ h23h){
  __shared__ float hs[64][68];      // 17.4 KiB
  __shared__ float wsd[64][64];     // 16 KiB
  const int tid = threadIdx.x;
  const int row0 = blockIdx.x * 64;

  // stage h tile: thread -> row r = tid>>2, col group cg = tid&3 (16 cols)
  {
    int r = tid >> 2, cg = tid & 3;
    int grow = row0 + r;
    bool ok = grow < N_NODES;
    const float4* hrow = (const float4*)(h1acth + (size_t)grow * D_HID + cg * 16);
    H8 q0, q1;
    q0.f = ok ? hrow[0] : make_float4(0,0,0,0);
    q1.f = ok ? hrow[1] : make_float4(0,0,0,0);
    float* dsth = &hs[r][cg * 16];
    #pragma unroll
    for (int j = 0; j < 4; ++j){
      float2 f = __half22float2(q0.h[j]);
      dsth[j * 2] = f.x; dsth[j * 2 + 1] = f.y;
    }
    #pragma unroll
    for (int j = 0; j < 4; ++j){
      float2 f = __half22float2(q1.h[j]);
      dsth[8 + j * 2] = f.x; dsth[8 + j * 2 + 1] = f.y;
    }
    // stage W tile: k = tid>>2, cols cg*16..+15 (cg<2 -> W2, else W3)
    int k = tid >> 2;
    const float* Wsrc = (cg < 2) ? W2 : W3;
    int cbase = (cg & 1) * 16;
    float4* dstw = (float4*)&wsd[k][cg * 16];
    const float4* srcw = (const float4*)&Wsrc[k * D_OUTF + cbase];
    #pragma unroll
    for (int j = 0; j < 4; ++j) dstw[j] = srcw[j];
  }
  __syncthreads();

  const int tc = tid & 15, tr = tid >> 4;
  float acc[4][4] = {};
  #pragma unroll
  for (int k4 = 0; k4 < 16; ++k4){
    float4 xr4[4];
    #pragma unroll
    for (int r = 0; r < 4; ++r)
      xr4[r] = *(float4*)&hs[(tr << 2) + r][k4 << 2];
    #pragma unroll
    for (int j = 0; j < 4; ++j){
      float4 w4 = *(float4*)&wsd[(k4 << 2) + j][tc << 2];
      #pragma unroll
      for (int r = 0; r < 4; ++r){
        float xk = (j == 0) ? xr4[r].x : (j == 1) ? xr4[r].y : (j == 2) ? xr4[r].z : xr4[r].w;
        acc[r][0] = fmaf(xk, w4.x, acc[r][0]);
        acc[r][1] = fmaf(xk, w4.y, acc[r][1]);
        acc[r][2] = fmaf(xk, w4.z, acc[r][2]);
        acc[r][3] = fmaf(xk, w4.w, acc[r][3]);
      }
    }
  }
  #pragma unroll
  for (int r = 0; r < 4; ++r){
    int row = row0 + (tr << 2) + r;
    if (row < N_NODES){
      H4 u;
      u.h[0] = __floats2half2_rn(acc[r][0], acc[r][1]);
      u.h[1] = __floats2half2_rn(acc[r][2], acc[r][3]);
      *(float2*)&h23h[(size_t)row * 64 + (tc << 2)] = u.f;
    }
  }
}

// ------- layers 2&3 aggregation (dual-edge half2) + relu + linear + var -------
__global__ __launch_bounds__(256) void k_agg23(const int* __restrict__ rowptr,
   const int* __restrict__ srcs,
   const __half* __restrict__ h23h,
   const float2* __restrict__ es23, float2* __restrict__ edinv2,
   const float* __restrict__ ed3,
   const float* __restrict__ b2, const float* __restrict__ b3,
   const float* __restrict__ Wlin, const float* __restrict__ blin,
   float* __restrict__ mean_out, float* __restrict__ var_out){
  __shared__ float sWl[D_OUTF * D_OUTF];
  int t = threadIdx.x, lane = t & 63, wv = t >> 6;
  int eslot = lane >> 5, c2 = lane & 31;
  int layer = c2 >> 4;                   // 0: layer-2 (mean), 1: layer-3 (var)
  int cc = (c2 & 15) << 1;               // channel pair within the 32-wide output
  for (int idx = t; idx < D_OUTF * D_OUTF; idx += 256) sWl[idx] = Wlin[idx];
  __syncthreads();

  int node = blockIdx.x * 4 + wv;
  int beg = rowptr[node], end = rowptr[node + 1];
  float edv = layer ? ed3[node] : edinv2[node].x;
  float2 a0 = {0,0}, a1 = {0,0}, a2 = {0,0}, a3 = {0,0};
  float ss = 0.f;
  #pragma unroll 1
  for (int base = beg; base < end; base += 16){
    int sA[8]; float2 v[8]; float p[8];
    int eb = base + (eslot << 3);
    #pragma unroll
    for (int u = 0; u < 8; ++u){
      int idx = eb + u;
      sA[u] = srcs[(idx < end) ? idx : beg];
    }
    #pragma unroll
    for (int u = 0; u < 8; ++u)
      v[u] = __half22float2(ldg_h2(h23h, (unsigned)(sA[u] * 128 + (c2 << 2))));
    #pragma unroll
    for (int u = 0; u < 8; ++u){
      float2 e2 = ldg_f2(es23, (unsigned)(sA[u] << 3));
      float esv = layer ? e2.y : e2.x;
      float e = __expf(leaky_relu(esv + edv));
      p[u] = (eb + u < end) ? e : 0.f;
    }
    #pragma unroll
    for (int u = 0; u < 8; ++u){
      ss += p[u];
      float2* a = (u & 3) == 0 ? &a0 : (u & 3) == 1 ? &a1 : (u & 3) == 2 ? &a2 : &a3;
      a->x = fmaf(p[u], v[u].x, a->x);
      a->y = fmaf(p[u], v[u].y, a->y);
    }
  }
  float2 acc2;
  acc2.x = (a0.x + a1.x) + (a2.x + a3.x);
  acc2.y = (a0.y + a1.y) + (a2.y + a3.y);
  acc2.x += __shfl_xor(acc2.x, 32, 64);
  acc2.y += __shfl_xor(acc2.y, 32, 64);
  ss    += __shfl_xor(ss, 32, 64);

  if (layer){  // layer-3 self loop
    float ps = __expf(leaky_relu(es23[node].y + ed3[node]));
    ss += ps;
    float2 hv = __half22float2(*(const __half2*)&h23h[(size_t)node * 64 + (c2 << 1)]);
    acc2.x = fmaf(ps, hv.x, acc2.x);
    acc2.y = fmaf(ps, hv.y, acc2.y);
  }
  float inv = 1.f / (ss + 1e-16f);
  if (layer){
    if (eslot == 0){
      float2 o = { acc2.x * inv + b3[cc], acc2.y * inv + b3[cc + 1] };
      *(float2*)&var_out[(size_t)node * D_OUTF + cc] = o;
    }
  } else {
    float2 mean;
    mean.x = acc2.x * inv + b2[cc];
    mean.y = acc2.y * inv + b2[cc + 1];
    mean.x = mean.x > 0.f ? mean.x : 0.f;
    mean.y = mean.y > 0.f ? mean.y : 0.f;
    float2 o = *(const float2*)&blin[cc];
    #pragma unroll
    for (int j2 = 0; j2 < 16; ++j2){
      float mjx = __shfl(mean.x, j2, 64);
      float mjy = __shfl(mean.y, j2, 64);
      float2 w0 = *(float2*)&sWl[(j2 * 2) * D_OUTF + cc];
      float2 w1 = *(float2*)&sWl[(j2 * 2 + 1) * D_OUTF + cc];
      o.x = fmaf(mjx, w0.x, o.x); o.x = fmaf(mjy, w1.x, o.x);
      o.y = fmaf(mjx, w0.y, o.y); o.y = fmaf(mjy, w1.y, o.y);
    }
    if (eslot == 0)
      *(float2*)&mean_out[(size_t)node * D_OUTF + cc] = o;
    if (lane == 0) edinv2[node].y = inv;
  }
}

// ------- alpha: flat edge-parallel, coalesced write -------
__global__ __launch_bounds__(256) void k_alpha(const int* __restrict__ src,
    const int* __restrict__ dst,
    const float2* __restrict__ es23, const float2* __restrict__ edinv2,
    float* __restrict__ alpha_out){
  int e = blockIdx.x * blockDim.x + threadIdx.x;
  if (e < N_EDGES){
    int s = src[e], d = dst[e];
    float2 tt = ldg_f2(edinv2, (unsigned)(d << 3));
    float esv = ldg_f2(es23, (unsigned)(s << 3)).x;
    alpha_out[e] = __expf(leaky_relu(esv + tt.x)) * tt.y;
  }
}

extern "C" void kernel_launch(void* const* d_in, const int* in_sizes, int n_in,
                              void* d_out, int out_size, void* d_ws, size_t ws_size,
                              hipStream_t stream) {
  const float* x   = (const float*)d_in[0];
  const int*   ei  = (const int*)d_in[1];
  const int*   src = ei;
  const int*   dst = ei + N_EDGES;
  const float* W1  = (const float*)d_in[2];
  const float* a1s = (const float*)d_in[3];
  const float* a1d = (const float*)d_in[4];
  const float* b1  = (const float*)d_in[5];
  const float* W2  = (const float*)d_in[6];
  const float* a2s = (const float*)d_in[7];
  const float* a2d = (const float*)d_in[8];
  const float* b2  = (const float*)d_in[9];
  const float* W3  = (const float*)d_in[10];
  const float* a3s = (const float*)d_in[11];
  const float* a3d = (const float*)d_in[12];
  const float* b3  = (const float*)d_in[13];
  const float* Wl  = (const float*)d_in[14];
  const float* bl  = (const float*)d_in[15];

  float* out       = (float*)d_out;
  float* mean_out  = out;
  float* var_out   = out + (size_t)N_NODES * D_OUTF;
  float* alpha_out = out + 2 * (size_t)N_NODES * D_OUTF;

  const int NSCAN = (N_NODES + 255) / 256;       // 196

  int* deg      = (int*)d_ws;                 // N
  int* wcount   = deg + N_NODES;              // N
  int* rowptr   = wcount + N_NODES;           // N+1
  int* bsum     = rowptr + (N_NODES + 1);     // NSCAN
  int* srcs     = bsum + NSCAN;               // E
  __half* h1h   = (__half*)(srcs + N_EDGES + 1);   // pad -> 8B aligned; reused as h23h
  __half* h1act = h1h + (size_t)N_NODES * 64;
  float* es1    = (float*)(h1act + (size_t)N_NODES * 64);
  float* ed1    = es1 + N_NODES;
  float* ed3    = ed1 + N_NODES;
  float* prew   = ed3 + N_NODES;              // 256 floats
  float2* es23  = (float2*)(prew + 256);
  float2* edinv2= es23 + N_NODES;
  __half* h23h  = h1h;                        // reuse (h1h dead after k_agg1)

  hipMemsetAsync(deg, 0, 2 * (size_t)N_NODES * sizeof(int), stream);

  k_deg   <<<(N_EDGES + 255) / 256, 256, 0, stream>>>(dst, deg);
  k_scan_a<<<NSCAN, 256, 0, stream>>>(deg, bsum);
  k_scan_b<<<1, 256, 0, stream>>>(bsum, NSCAN, W2, W3, a2s, a2d, a3s, a3d, prew);
  k_scan_c<<<NSCAN, 256, 0, stream>>>(deg, bsum, rowptr);
  k_fill  <<<(N_EDGES + 255) / 256, 256, 0, stream>>>(src, dst, rowptr, wcount, srcs);

  k_gemm1<<<(N_NODES + MT - 1) / MT, 256, 0, stream>>>(x, W1, a1s, a1d, h1h, es1, ed1);
  k_agg1 <<<N_NODES / 4, 256, 0, stream>>>(rowptr, srcs, h1h, es1, ed1, b1, prew,
                                           h1act, es23, edinv2, ed3);
  k_gemm23<<<(N_NODES + 63) / 64, 256, 0, stream>>>(h1act, W2, W3, h23h);
  k_agg23<<<N_NODES / 4, 256, 0, stream>>>(rowptr, srcs, h23h,
                                           es23, edinv2, ed3, b2, b3, Wl, bl,
                                           mean_out, var_out);
  k_alpha<<<(N_EDGES + 255) / 256, 256, 0, stream>>>(src, dst, es23, edinv2, alpha_out);
}